// Round 4
// baseline (231.383 us; speedup 1.0000x reference)
//
#include <hip/hip_runtime.h>

#define AS1(p) ((const __attribute__((address_space(1))) void*)(p))
#define AS3(p) ((__attribute__((address_space(3))) void*)(p))

typedef unsigned short u16;
typedef __bf16 bf16x8 __attribute__((ext_vector_type(8)));
typedef short s16x8 __attribute__((ext_vector_type(8)));
typedef float f32x4 __attribute__((ext_vector_type(4)));
typedef unsigned short u16x4 __attribute__((ext_vector_type(4)));
typedef unsigned short u16x8v __attribute__((ext_vector_type(8)));

__device__ __forceinline__ u16 f2bf(float x) {
    unsigned u = __float_as_uint(x);
    unsigned r = (u + 0x7FFFu + ((u >> 16) & 1u)) >> 16;
    return (u16)r;
}

template <typename V8>
__device__ __forceinline__ auto mfma_sel(V8 a, V8 b, f32x4 c, int)
    -> decltype(__builtin_amdgcn_mfma_f32_16x16x32_bf16(a, b, c, 0, 0, 0))
{
    return __builtin_amdgcn_mfma_f32_16x16x32_bf16(a, b, c, 0, 0, 0);
}
template <typename V8>
__device__ __forceinline__ f32x4 mfma_sel(V8 a, V8 b, f32x4 c, long)
{
    s16x8 a2 = __builtin_bit_cast(s16x8, a);
    s16x8 b2 = __builtin_bit_cast(s16x8, b);
    return __builtin_amdgcn_mfma_f32_16x16x32_bf16(a2, b2, c, 0, 0, 0);
}
__device__ __forceinline__ f32x4 mfma16x16x32(bf16x8 a, bf16x8 b, f32x4 c)
{
    return mfma_sel(a, b, c, 0);
}

// ---------------- fp32 -> bf16 convert ----------------
__global__ __launch_bounds__(256) void cvt_bf16_kernel(const float* __restrict__ in,
                                                       u16* __restrict__ out, int n4)
{
    int i = blockIdx.x * 256 + threadIdx.x;
    if (i >= n4) return;
    float4 f = ((const float4*)in)[i];
    u16x4 o;
    o.x = f2bf(f.x); o.y = f2bf(f.y); o.z = f2bf(f.z); o.w = f2bf(f.w);
    ((u16x4*)out)[i] = o;
}

// ---------------- bf16 transpose: in[R][C] -> out[C][R], 64x64 tiles ----------------
__global__ __launch_bounds__(256) void transpose16(const u16* __restrict__ in,
                                                   u16* __restrict__ out, int R, int C)
{
    __shared__ u16 tl[64][65];
    const int tr0 = blockIdx.y * 64, tc0 = blockIdx.x * 64;
    const int t = threadIdx.x;
    const int r = t >> 2, c4 = (t & 3) << 4;

    const u16* src = in + (size_t)(tr0 + r) * C + tc0 + c4;
    u16x8v a0 = *(const u16x8v*)src;
    u16x8v a1 = *(const u16x8v*)(src + 8);
    #pragma unroll
    for (int j = 0; j < 8; ++j) { tl[r][c4 + j] = a0[j]; tl[r][c4 + 8 + j] = a1[j]; }
    __syncthreads();

    u16x8v b0, b1;
    #pragma unroll
    for (int j = 0; j < 8; ++j) { b0[j] = tl[c4 + j][r]; b1[j] = tl[c4 + 8 + j][r]; }
    u16* dst = out + (size_t)(tc0 + r) * R + tr0 + c4;
    *(u16x8v*)dst = b0;
    *(u16x8v*)(dst + 8) = b1;
}

// ============ pipelined NT GEMM: C[m][n] = sum_k A[m][k]*B[n][k] ============
// 128 x (TN*64) tile, BK=64, 512 threads (2M x 4N waves, 64 x TN*16 per wave).
// TRIPLE-buffered LDS, 2-tile stage lead, counted vmcnt (T4), per-kk phase
// split with barriers (T3-style) + setprio around MFMA (T5) + T2 swizzle.
// Race proof: STAGE at iter t writes buf[(t+2)%3] == buf[(t-1)%3], whose last
// reads finished before iter t-1's end barrier. Reads at iter t hit buf[t%3],
// staged at t-2; every wave executed vmcnt(L) (only t+1-tile loads newer)
// before iter t-1's final barriers, so all waves' t-tile loads have landed.
// T2 swizzle (rule 21): linear LDS dest (global_load_lds requirement),
// inverse-XOR'd global SOURCE slot, XOR'd read: slot16B ^= (row&7).
#define GBM 128
#define GBK 64

template <int TN, int BIAS, int OUTBF16, int CSKIP, int CKB>
__global__ __launch_bounds__(512, 2)
void gemm_nt2(const u16* __restrict__ A, const u16* __restrict__ B,
              void* __restrict__ Cv, const float* __restrict__ bias,
              void* __restrict__ C2, const float* __restrict__ bias2,
              void* __restrict__ C3, const float* __restrict__ bias3,
              int M, int N, int K, int lda, int ldb, int ldc,
              long long sA, long long sB, long long sC, float scale)
{
    constexpr int BN    = TN * 64;
    constexpr int ABUF_ = GBM * GBK * 2;        // 16 KB
    constexpr int BBUF_ = BN * GBK * 2;         // TN*8 KB
    constexpr int TBUF_ = ABUF_ + BBUF_;
    constexpr int BL    = TN;                   // B stage loads per thread
    extern __shared__ char smem[];

    int by = blockIdx.y;
    if (CKB) by = gridDim.y - 1 - by;           // longest-K blocks first
    const int m0 = by * GBM;
    const int n0 = blockIdx.x * BN;
    if (CSKIP && n0 > m0 + GBM - 1) return;

    const int z = blockIdx.z;
    A += (size_t)z * (size_t)sA;
    B += (size_t)z * (size_t)sB;

    const int t = threadIdx.x;
    const int lane = t & 63;
    const int w = t >> 6;            // 0..7
    const int wr = w >> 2;           // 0..1 (M)
    const int wc = w & 3;            // 0..3 (N)
    const int fr = lane & 15, fg = lane >> 4;

    int Keff = K;
    if (CKB) { Keff = m0 + GBM; if (Keff > K) Keff = K; }
    const int nk = Keff / GBK;       // >= 2 for all our shapes

    f32x4 acc[4][TN] = {};

    auto STAGE = [&](int kt, int buf, int ph) {
        const int k0 = kt * GBK;
        char* sb = smem + buf * TBUF_;
        if (ph == 0) {
            #pragma unroll
            for (int i = 0; i < 2; ++i) {          // A: 128x64 = 1024 chunks
                int c = t + i * 512;
                int row = c >> 3;
                int sl = (c & 7) ^ (row & 7);      // inverse-swizzled source slot
                __builtin_amdgcn_global_load_lds(
                    AS1(A + (size_t)(m0 + row) * lda + k0 + sl * 8),
                    AS3(sb + c * 16), 16, 0, 0);
            }
        }
        const int ib = ph ? BL / 2 : 0;
        const int ie = ph ? BL : BL / 2;
        #pragma unroll
        for (int i = ib; i < ie; ++i) {            // B: BN x 64 chunks
            int c = t + i * 512;
            int row = c >> 3;
            int sl = (c & 7) ^ (row & 7);
            __builtin_amdgcn_global_load_lds(
                AS1(B + (size_t)(n0 + row) * ldb + k0 + sl * 8),
                AS3(sb + ABUF_ + c * 16), 16, 0, 0);
        }
    };

    // prologue: stage tiles 0,1; confirm tile 0 (tile 1's L loads stay in flight)
    STAGE(0, 0, 0); STAGE(0, 0, 1);
    STAGE(1, 1, 0); STAGE(1, 1, 1);
    if (TN == 4) asm volatile("s_waitcnt vmcnt(6)" ::: "memory");
    else         asm volatile("s_waitcnt vmcnt(4)" ::: "memory");
    __builtin_amdgcn_s_barrier();

    int cur = 0;
    for (int kt = 0; kt < nk; ++kt) {
        int pb = cur + 2; if (pb >= 3) pb -= 3;
        const bool pf = (kt + 2 < nk);
        const char* la = smem + cur * TBUF_;
        const char* lb = la + ABUF_;

        #pragma unroll
        for (int kk = 0; kk < GBK; kk += 32) {     // two phases per K-tile
            const int ph = kk >> 5;
            const int cs = (kk >> 3) + fg;         // column 16B-slot 0..7
            bf16x8 af[4], bfv[TN];
            #pragma unroll
            for (int mi = 0; mi < 4; ++mi) {
                int row = wr * 64 + mi * 16 + fr;
                af[mi] = *(const bf16x8*)(la + (row << 7) + ((cs ^ (row & 7)) << 4));
            }
            #pragma unroll
            for (int ni = 0; ni < TN; ++ni) {
                int row = wc * (TN * 16) + ni * 16 + fr;
                bfv[ni] = *(const bf16x8*)(lb + (row << 7) + ((cs ^ (row & 7)) << 4));
            }
            if (pf) STAGE(kt + 2, pb, ph);
            if (ph == 1) {                         // tile-end: confirm t+1 landed
                if (pf) {
                    if (TN == 4) asm volatile("s_waitcnt vmcnt(6)" ::: "memory");
                    else         asm volatile("s_waitcnt vmcnt(4)" ::: "memory");
                } else {
                    asm volatile("s_waitcnt vmcnt(0)" ::: "memory");
                }
            }
            __builtin_amdgcn_s_barrier();
            __builtin_amdgcn_s_setprio(1);
            #pragma unroll
            for (int mi = 0; mi < 4; ++mi)
                #pragma unroll
                for (int ni = 0; ni < TN; ++ni)
                    acc[mi][ni] = mfma16x16x32(af[mi], bfv[ni], acc[mi][ni]);
            __builtin_amdgcn_s_setprio(0);
            __builtin_amdgcn_s_barrier();
        }
        ++cur; if (cur >= 3) cur = 0;
    }

    // ---- epilogue: C/D layout col=lane&15, row=(lane>>4)*4+reg ----
    #pragma unroll
    for (int mi = 0; mi < 4; ++mi) {
        #pragma unroll
        for (int ni = 0; ni < TN; ++ni) {
            int col = n0 + wc * (TN * 16) + ni * 16 + fr;
            u16* dst16 = (u16*)Cv;
            float* dst32 = (float*)Cv;
            float bval = 0.f, sc_ = scale;
            int ccol = col;
            if (BIAS == 1) bval = bias[col];
            if (BIAS == 3) {
                int seg = col >> 10; ccol = col & 1023;
                if (seg == 0)      { dst16 = (u16*)Cv; bval = bias[ccol]; }
                else if (seg == 1) { dst16 = (u16*)C2; bval = bias2[ccol]; sc_ = 1.f; }
                else               { dst16 = (u16*)C3; bval = bias3[ccol]; sc_ = 1.f; }
            }
            #pragma unroll
            for (int j = 0; j < 4; ++j) {
                int row = m0 + wr * 64 + mi * 16 + fg * 4 + j;
                float v = (acc[mi][ni][j] + bval) * sc_;
                size_t off = (size_t)z * (size_t)sC + (size_t)row * ldc + ccol;
                if (OUTBF16 || BIAS == 3) dst16[off] = f2bf(v);
                else                      dst32[off] = v;
            }
        }
    }
}

// ---------------- causal softmax, in-place fp32 -> bf16 P ----------------
__device__ __forceinline__ float waveMax(float v) {
    #pragma unroll
    for (int o = 32; o > 0; o >>= 1) v = fmaxf(v, __shfl_xor(v, o));
    return v;
}
__device__ __forceinline__ float waveSum(float v) {
    #pragma unroll
    for (int o = 32; o > 0; o >>= 1) v += __shfl_xor(v, o);
    return v;
}

__global__ __launch_bounds__(256) void softmax_causal_kernel(float* __restrict__ scores, int S)
{
    __shared__ float red[4];
    const int gb = blockIdx.x;
    const int b = gb / S;
    const int i = gb - b * S;
    float* srow = scores + (size_t)b * S * S + (size_t)i * S;
    u16* prow = (u16*)srow;
    const int t = threadIdx.x;
    const int jlim = ((i >> 7) + 1) << 7;   // == PV's Keff for this row's block

    float vals[8];
    float mx = -1e30f;
    #pragma unroll
    for (int s = 0; s < 8; ++s) {
        int j = t + (s << 8);
        float x = -1e30f;
        if (j <= i) x = srow[j];
        vals[s] = x;
        mx = fmaxf(mx, x);
    }
    mx = waveMax(mx);
    const int wv = t >> 6;
    if ((t & 63) == 0) red[wv] = mx;
    __syncthreads();
    mx = fmaxf(fmaxf(red[0], red[1]), fmaxf(red[2], red[3]));
    __syncthreads();

    float sum = 0.f;
    #pragma unroll
    for (int s = 0; s < 8; ++s) {
        float e = (vals[s] > -1e29f) ? __expf(vals[s] - mx) : 0.f;
        vals[s] = e;
        sum += e;
    }
    sum = waveSum(sum);
    if ((t & 63) == 0) red[wv] = sum;
    __syncthreads();
    sum = red[0] + red[1] + red[2] + red[3];
    const float inv = 1.f / sum;
    __syncthreads();

    #pragma unroll
    for (int s = 0; s < 8; ++s) {
        int j = t + (s << 8);
        if (j < jlim) prow[j] = f2bf(vals[s] * inv);
    }
}

// ---------------- host launcher ----------------
extern "C" void kernel_launch(void* const* d_in, const int* in_sizes, int n_in,
                              void* d_out, int out_size, void* d_ws, size_t ws_size,
                              hipStream_t stream)
{
    (void)in_sizes; (void)n_in; (void)out_size;
    const float* x  = (const float*)d_in[0];
    const float* Wq = (const float*)d_in[1];
    const float* bq = (const float*)d_in[2];
    const float* Wk = (const float*)d_in[3];
    const float* bk = (const float*)d_in[4];
    const float* Wv = (const float*)d_in[5];
    const float* bv = (const float*)d_in[6];
    const float* Wp = (const float*)d_in[7];
    const float* bp = (const float*)d_in[8];

    const int D = 1024, S = 2048, B = 4;
    const int M = B * S; // 8192

    char* p = (char*)d_ws;
    u16* xb   = (u16*)p; p += (size_t)M * D * 2;
    u16* Wcat = (u16*)p; p += (size_t)3 * D * D * 2;
    u16* Wpb  = (u16*)p; p += (size_t)D * D * 2;
    u16* qb   = (u16*)p; p += (size_t)M * D * 2;
    u16* kb   = (u16*)p; p += (size_t)M * D * 2;
    u16* vTb  = (u16*)p; p += (size_t)M * D * 2;   // vT[d][b*S+s], ld=M
    u16* vb   = (u16*)p;                           // dead before scores
    float* sc = (float*)p;                         // scores region (overlaps vb)
    u16* attnb = xb;                               // alias: x dead after QKV

    const size_t fixed = (size_t)p - (size_t)d_ws;
    const size_t sb1   = (size_t)S * S * 4;
    int zb = (ws_size >= fixed + 4 * sb1) ? 4 : 1;

    const int LDS4 = 3 * (16384 + 32768);   // TN=4: 144 KB
    const int LDS2 = 3 * (16384 + 16384);   // TN=2: 96 KB

    hipFuncSetAttribute((const void*)gemm_nt2<4, 3, 1, 0, 0>,
                        hipFuncAttributeMaxDynamicSharedMemorySize, LDS4);
    hipFuncSetAttribute((const void*)gemm_nt2<2, 0, 0, 1, 0>,
                        hipFuncAttributeMaxDynamicSharedMemorySize, LDS2);
    hipFuncSetAttribute((const void*)gemm_nt2<2, 0, 1, 0, 1>,
                        hipFuncAttributeMaxDynamicSharedMemorySize, LDS2);
    hipFuncSetAttribute((const void*)gemm_nt2<2, 1, 0, 0, 0>,
                        hipFuncAttributeMaxDynamicSharedMemorySize, LDS2);

    // fp32 -> bf16
    cvt_bf16_kernel<<<(M * D / 4 + 255) / 256, 256, 0, stream>>>(x, xb, M * D / 4);
    cvt_bf16_kernel<<<(D * D / 4 + 255) / 256, 256, 0, stream>>>(Wq, Wcat, D * D / 4);
    cvt_bf16_kernel<<<(D * D / 4 + 255) / 256, 256, 0, stream>>>(Wk, Wcat + (size_t)D * D, D * D / 4);
    cvt_bf16_kernel<<<(D * D / 4 + 255) / 256, 256, 0, stream>>>(Wv, Wcat + (size_t)2 * D * D, D * D / 4);
    cvt_bf16_kernel<<<(D * D / 4 + 255) / 256, 256, 0, stream>>>(Wp, Wpb, D * D / 4);

    // fused QKV: [q|k|v] = x Wcat^T + [bq|bk|bv]; q scaled by 1/sqrt(D)
    gemm_nt2<4, 3, 1, 0, 0><<<dim3(3 * D / 256, M / GBM, 1), 512, LDS4, stream>>>(
        xb, Wcat, qb, bq, kb, bk, vb, bv,
        M, 3 * D, D, D, D, D, 0, 0, 0, 0.03125f);

    // vT = v^T
    transpose16<<<dim3(D / 64, M / 64), 256, 0, stream>>>(vb, vTb, M, D);

    for (int b0 = 0; b0 < B; b0 += zb) {
        // scores = q k^T (lower-triangular 128x128 tiles only), fp32
        gemm_nt2<2, 0, 0, 1, 0><<<dim3(S / 128, S / GBM, zb), 512, LDS2, stream>>>(
            qb + (size_t)b0 * S * D, kb + (size_t)b0 * S * D, sc, nullptr,
            nullptr, nullptr, nullptr, nullptr,
            S, S, D, D, D, S,
            (long long)S * D, (long long)S * D, (long long)S * S, 1.0f);
        // causal softmax, write P (bf16) in place
        softmax_causal_kernel<<<zb * S, 256, 0, stream>>>(sc, S);
        // attn_out = P v  (A = P bf16 ld 2S; B = vT rows, K causally bounded)
        gemm_nt2<2, 0, 1, 0, 1><<<dim3(D / 128, S / GBM, zb), 512, LDS2, stream>>>(
            (const u16*)sc, vTb + (size_t)b0 * S, attnb + (size_t)b0 * S * D, nullptr,
            nullptr, nullptr, nullptr, nullptr,
            S, D, S, 2 * S, M, D,
            (long long)2 * S * S, (long long)S, (long long)S * D, 1.0f);
    }

    // out = attn_out Wp^T + bp  (fp32 output)
    gemm_nt2<2, 1, 0, 0, 0><<<dim3(D / 128, M / GBM, 1), 512, LDS2, stream>>>(
        attnb, Wpb, d_out, bp, nullptr, nullptr, nullptr, nullptr,
        M, D, D, D, D, D, 0, 0, 0, 1.0f);
}

// Round 5
// 205.300 us; speedup vs baseline: 1.1270x; 1.1270x over previous
//
#include <hip/hip_runtime.h>

#define AS1(p) ((const __attribute__((address_space(1))) void*)(p))
#define AS3(p) ((__attribute__((address_space(3))) void*)(p))

typedef unsigned short u16;
typedef __bf16 bf16x8 __attribute__((ext_vector_type(8)));
typedef short s16x8 __attribute__((ext_vector_type(8)));
typedef float f32x4 __attribute__((ext_vector_type(4)));
typedef unsigned short u16x4 __attribute__((ext_vector_type(4)));

__device__ __forceinline__ u16 f2bf(float x) {
    unsigned u = __float_as_uint(x);
    unsigned r = (u + 0x7FFFu + ((u >> 16) & 1u)) >> 16;
    return (u16)r;
}

template <typename V8>
__device__ __forceinline__ auto mfma_sel(V8 a, V8 b, f32x4 c, int)
    -> decltype(__builtin_amdgcn_mfma_f32_16x16x32_bf16(a, b, c, 0, 0, 0))
{
    return __builtin_amdgcn_mfma_f32_16x16x32_bf16(a, b, c, 0, 0, 0);
}
template <typename V8>
__device__ __forceinline__ f32x4 mfma_sel(V8 a, V8 b, f32x4 c, long)
{
    s16x8 a2 = __builtin_bit_cast(s16x8, a);
    s16x8 b2 = __builtin_bit_cast(s16x8, b);
    return __builtin_amdgcn_mfma_f32_16x16x32_bf16(a2, b2, c, 0, 0, 0);
}
__device__ __forceinline__ f32x4 mfma16x16x32(bf16x8 a, bf16x8 b, f32x4 c)
{
    return mfma_sel(a, b, c, 0);
}

// ---------------- fp32 -> bf16 converts ----------------
__global__ __launch_bounds__(256) void cvt_bf16_kernel(const float* __restrict__ in,
                                                       u16* __restrict__ out, int n4)
{
    int i = blockIdx.x * 256 + threadIdx.x;
    if (i >= n4) return;
    float4 f = ((const float4*)in)[i];
    u16x4 o;
    o.x = f2bf(f.x); o.y = f2bf(f.y); o.z = f2bf(f.z); o.w = f2bf(f.w);
    ((u16x4*)out)[i] = o;
}

// all 4 weight matrices in one launch; by selects source/dest
__global__ __launch_bounds__(256) void cvt_w4_kernel(const float* __restrict__ Wq,
                                                     const float* __restrict__ Wk,
                                                     const float* __restrict__ Wv,
                                                     const float* __restrict__ Wp,
                                                     u16* __restrict__ Wcat,
                                                     u16* __restrict__ Wpb, int n4)
{
    int i = blockIdx.x * 256 + threadIdx.x;
    if (i >= n4) return;
    const int by = blockIdx.y;
    const float* src = (by == 0) ? Wq : (by == 1) ? Wk : (by == 2) ? Wv : Wp;
    u16* dst = (by == 3) ? Wpb : (Wcat + (size_t)by * n4 * 4);
    float4 f = ((const float4*)src)[i];
    u16x4 o;
    o.x = f2bf(f.x); o.y = f2bf(f.y); o.z = f2bf(f.z); o.w = f2bf(f.w);
    ((u16x4*)dst)[i] = o;
}

// ============ r3-proven pipelined NT GEMM (128x256, BK=64) ============
// TRIPLE-buffered LDS (144 KB dynamic), 2-tile stage lead, counted vmcnt.
// Race proof: STAGE at iter t writes buf[(t+2)%3] == buf[(t-1)%3], whose last
// reads finished before iter t-1's end barrier. Reads at iter t hit buf[t%3],
// staged at iter t-2 and confirmed by iter t-1's vmcnt(6)+barrier.
// T2 swizzle (rule 21): linear LDS dest, inverse-XOR'd global SOURCE slot,
// XOR'd read: slot16B ^= (row&7).
#define GBM 128
#define GBN 256
#define GBK 64
#define ABUF 16384           // 128*64*2
#define BBUF 32768           // 256*64*2
#define TBUF (ABUF + BBUF)   // 48 KB per buffer
#define LDS_NT2 (3 * TBUF)   // 147456

template <int BIAS, int OUTBF16, int CSKIP, int CKB>
__global__ __launch_bounds__(512, 2)
void gemm_nt2(const u16* __restrict__ A, const u16* __restrict__ B,
              void* __restrict__ Cv, const float* __restrict__ bias,
              int M, int N, int K, int lda, int ldb, int ldc,
              long long sA, long long sB, long long sC, float scale)
{
    extern __shared__ char smem[];

    int by = blockIdx.y;
    if (CKB) by = gridDim.y - 1 - by;       // longest-K blocks first
    const int m0 = by * GBM;
    const int n0 = blockIdx.x * GBN;
    if (CSKIP && n0 > m0 + GBM - 1) return;

    const int z = blockIdx.z;
    A += (size_t)z * (size_t)sA;
    B += (size_t)z * (size_t)sB;

    const int t = threadIdx.x;
    const int lane = t & 63;
    const int w = t >> 6;
    const int wr = w >> 2;           // 0..1 (M)
    const int wc = w & 3;            // 0..3 (N)
    const int fr = lane & 15, fg = lane >> 4;

    int Keff = K;
    if (CKB) { Keff = m0 + GBM; if (Keff > K) Keff = K; }
    const int nk = Keff / GBK;

    f32x4 acc[4][4] = {};

    auto STAGE = [&](int kt, int buf) {
        const int k0 = kt * GBK;
        char* sb = smem + buf * TBUF;
        #pragma unroll
        for (int i = 0; i < 2; ++i) {      // A: 128x64 = 1024 16B chunks
            int c = t + i * 512;
            int row = c >> 3;
            int sl = (c & 7) ^ (row & 7);
            __builtin_amdgcn_global_load_lds(
                AS1(A + (size_t)(m0 + row) * lda + k0 + sl * 8),
                AS3(sb + c * 16), 16, 0, 0);
        }
        #pragma unroll
        for (int i = 0; i < 4; ++i) {      // B: 256x64 = 2048 16B chunks
            int c = t + i * 512;
            int row = c >> 3;
            int sl = (c & 7) ^ (row & 7);
            __builtin_amdgcn_global_load_lds(
                AS1(B + (size_t)(n0 + row) * ldb + k0 + sl * 8),
                AS3(sb + ABUF + c * 16), 16, 0, 0);
        }
    };

    STAGE(0, 0);
    STAGE(1, 1);
    asm volatile("s_waitcnt vmcnt(6)" ::: "memory");
    __builtin_amdgcn_s_barrier();

    int cur = 0;
    for (int kt = 0; kt < nk; ++kt) {
        int pb = cur + 2; if (pb >= 3) pb -= 3;
        const bool pf = (kt + 2 < nk);
        if (pf) STAGE(kt + 2, pb);

        const char* la = smem + cur * TBUF;
        const char* lb = la + ABUF;
        #pragma unroll
        for (int kk = 0; kk < GBK; kk += 32) {
            const int cs = (kk >> 3) + fg;
            bf16x8 af[4], bfv[4];
            #pragma unroll
            for (int mi = 0; mi < 4; ++mi) {
                int row = wr * 64 + mi * 16 + fr;
                af[mi] = *(const bf16x8*)(la + (row << 7) + ((cs ^ (row & 7)) << 4));
            }
            #pragma unroll
            for (int ni = 0; ni < 4; ++ni) {
                int row = wc * 64 + ni * 16 + fr;
                bfv[ni] = *(const bf16x8*)(lb + (row << 7) + ((cs ^ (row & 7)) << 4));
            }
            __builtin_amdgcn_s_setprio(1);
            #pragma unroll
            for (int mi = 0; mi < 4; ++mi)
                #pragma unroll
                for (int ni = 0; ni < 4; ++ni)
                    acc[mi][ni] = mfma16x16x32(af[mi], bfv[ni], acc[mi][ni]);
            __builtin_amdgcn_s_setprio(0);
        }

        if (pf) asm volatile("s_waitcnt vmcnt(6)" ::: "memory");
        else    asm volatile("s_waitcnt vmcnt(0)" ::: "memory");
        __builtin_amdgcn_s_barrier();
        ++cur; if (cur >= 3) cur = 0;
    }

    // epilogue: C/D layout col=lane&15, row=(lane>>4)*4+reg
    #pragma unroll
    for (int mi = 0; mi < 4; ++mi) {
        #pragma unroll
        for (int ni = 0; ni < 4; ++ni) {
            int col = n0 + wc * 64 + ni * 16 + fr;
            float bval = (BIAS == 1) ? bias[col] : 0.f;
            #pragma unroll
            for (int j = 0; j < 4; ++j) {
                int row = m0 + wr * 64 + mi * 16 + fg * 4 + j;
                float v = (acc[mi][ni][j] + bval) * scale;
                size_t off = (size_t)z * (size_t)sC + (size_t)row * ldc + col;
                if (OUTBF16) ((u16*)Cv)[off] = f2bf(v);
                else         ((float*)Cv)[off] = v;
            }
        }
    }
}

// ============ QKV GEMM: 256x256, BK=32, same triple-buffer schedule ============
// 8 waves 2M x 4N, per-wave 128x64 (FM=8, FN=4). LDS 3 x 32KB = 96 KB.
// Same invariants as gemm_nt2 (2-tile lead, counted vmcnt(4)).
// Row = 4 x 16B slots; swizzle slot ^= (row>>1)&3 (2 lanes/bank, free).
// Fused epilogue: q (scaled, +bq), k (+bk), vT (transposed write, +bv).
#define QBM 256
#define QBK 32
#define QABUF 16384          // 256*32*2
#define QTBUF 32768
#define QLDS  98304          // 3 buffers

__global__ __launch_bounds__(512, 2)
void gemm256_qkv(const u16* __restrict__ A, const u16* __restrict__ B,
                 u16* __restrict__ q, const float* __restrict__ bq,
                 u16* __restrict__ ko, const float* __restrict__ bk,
                 u16* __restrict__ vT, const float* __restrict__ bv,
                 int M, int K, float qscale)
{
    extern __shared__ char smem[];

    // bijective XCD swizzle (nwg = 384, %8 == 0)
    const int gx = gridDim.x;
    const int nwg = gx * gridDim.y;
    int id = blockIdx.y * gx + blockIdx.x;
    id = (id & 7) * (nwg >> 3) + (id >> 3);
    const int bx = id % gx;
    const int by = id / gx;
    const int m0 = by * QBM;
    const int n0 = bx * 256;

    const int t = threadIdx.x;
    const int lane = t & 63;
    const int w = t >> 6;
    const int wr = w >> 2;           // 0..1
    const int wc = w & 3;            // 0..3
    const int fr = lane & 15, fg = lane >> 4;

    const int nk = K / QBK;          // 32

    f32x4 acc[8][4] = {};

    auto STAGE = [&](int kt, int buf) {
        const int k0 = kt * QBK;
        char* sb = smem + buf * QTBUF;
        #pragma unroll
        for (int i = 0; i < 2; ++i) {      // A: 256x32 = 1024 16B chunks
            int c = t + i * 512;
            int row = c >> 2;
            int sl = (c & 3) ^ ((row >> 1) & 3);
            __builtin_amdgcn_global_load_lds(
                AS1(A + (size_t)(m0 + row) * K + k0 + sl * 8),
                AS3(sb + c * 16), 16, 0, 0);
        }
        #pragma unroll
        for (int i = 0; i < 2; ++i) {      // B: 256x32
            int c = t + i * 512;
            int row = c >> 2;
            int sl = (c & 3) ^ ((row >> 1) & 3);
            __builtin_amdgcn_global_load_lds(
                AS1(B + (size_t)(n0 + row) * K + k0 + sl * 8),
                AS3(sb + QABUF + c * 16), 16, 0, 0);
        }
    };

    STAGE(0, 0);
    STAGE(1, 1);
    asm volatile("s_waitcnt vmcnt(4)" ::: "memory");
    __builtin_amdgcn_s_barrier();

    int cur = 0;
    for (int kt = 0; kt < nk; ++kt) {
        int pb = cur + 2; if (pb >= 3) pb -= 3;
        const bool pf = (kt + 2 < nk);
        if (pf) STAGE(kt + 2, pb);

        const char* la = smem + cur * QTBUF;
        const char* lb = la + QABUF;
        bf16x8 af[8], bfv[4];
        #pragma unroll
        for (int mi = 0; mi < 8; ++mi) {
            int row = wr * 128 + mi * 16 + fr;
            af[mi] = *(const bf16x8*)(la + (row << 6) + ((fg ^ ((row >> 1) & 3)) << 4));
        }
        #pragma unroll
        for (int ni = 0; ni < 4; ++ni) {
            int row = wc * 64 + ni * 16 + fr;
            bfv[ni] = *(const bf16x8*)(lb + (row << 6) + ((fg ^ ((row >> 1) & 3)) << 4));
        }
        __builtin_amdgcn_s_setprio(1);
        #pragma unroll
        for (int mi = 0; mi < 8; ++mi)
            #pragma unroll
            for (int ni = 0; ni < 4; ++ni)
                acc[mi][ni] = mfma16x16x32(af[mi], bfv[ni], acc[mi][ni]);
        __builtin_amdgcn_s_setprio(0);

        if (pf) asm volatile("s_waitcnt vmcnt(4)" ::: "memory");
        else    asm volatile("s_waitcnt vmcnt(0)" ::: "memory");
        __builtin_amdgcn_s_barrier();
        ++cur; if (cur >= 3) cur = 0;
    }

    // epilogue; seg is block-uniform (n0 multiple of 256, D=1024)
    const int seg = n0 >> 10;
    #pragma unroll
    for (int mi = 0; mi < 8; ++mi) {
        #pragma unroll
        for (int ni = 0; ni < 4; ++ni) {
            int col = n0 + wc * 64 + ni * 16 + fr;
            int ccol = col & 1023;
            int row0 = m0 + wr * 128 + mi * 16 + fg * 4;
            if (seg == 0) {
                float b = bq[ccol];
                #pragma unroll
                for (int j = 0; j < 4; ++j)
                    q[(size_t)(row0 + j) * 1024 + ccol] = f2bf((acc[mi][ni][j] + b) * qscale);
            } else if (seg == 1) {
                float b = bk[ccol];
                #pragma unroll
                for (int j = 0; j < 4; ++j)
                    ko[(size_t)(row0 + j) * 1024 + ccol] = f2bf(acc[mi][ni][j] + b);
            } else {
                float b = bv[ccol];
                u16x4 o;
                #pragma unroll
                for (int j = 0; j < 4; ++j) o[j] = f2bf(acc[mi][ni][j] + b);
                *(u16x4*)&vT[(size_t)ccol * M + row0] = o;   // transposed write
            }
        }
    }
}

// ---------------- causal softmax, in-place fp32 -> bf16 P ----------------
__device__ __forceinline__ float waveMax(float v) {
    #pragma unroll
    for (int o = 32; o > 0; o >>= 1) v = fmaxf(v, __shfl_xor(v, o));
    return v;
}
__device__ __forceinline__ float waveSum(float v) {
    #pragma unroll
    for (int o = 32; o > 0; o >>= 1) v += __shfl_xor(v, o);
    return v;
}

__global__ __launch_bounds__(256) void softmax_causal_kernel(float* __restrict__ scores, int S)
{
    __shared__ float red[4];
    const int gb = blockIdx.x;
    const int b = gb / S;
    const int i = gb - b * S;
    float* srow = scores + (size_t)b * S * S + (size_t)i * S;
    u16* prow = (u16*)srow;
    const int t = threadIdx.x;
    const int jlim = ((i >> 7) + 1) << 7;

    float vals[8];
    float mx = -1e30f;
    #pragma unroll
    for (int s = 0; s < 8; ++s) {
        int j = t + (s << 8);
        float x = -1e30f;
        if (j <= i) x = srow[j];
        vals[s] = x;
        mx = fmaxf(mx, x);
    }
    mx = waveMax(mx);
    const int wv = t >> 6;
    if ((t & 63) == 0) red[wv] = mx;
    __syncthreads();
    mx = fmaxf(fmaxf(red[0], red[1]), fmaxf(red[2], red[3]));
    __syncthreads();

    float sum = 0.f;
    #pragma unroll
    for (int s = 0; s < 8; ++s) {
        float e = (vals[s] > -1e29f) ? __expf(vals[s] - mx) : 0.f;
        vals[s] = e;
        sum += e;
    }
    sum = waveSum(sum);
    if ((t & 63) == 0) red[wv] = sum;
    __syncthreads();
    sum = red[0] + red[1] + red[2] + red[3];
    const float inv = 1.f / sum;
    __syncthreads();

    #pragma unroll
    for (int s = 0; s < 8; ++s) {
        int j = t + (s << 8);
        if (j < jlim) prow[j] = f2bf(vals[s] * inv);
    }
}

// ---------------- host launcher ----------------
extern "C" void kernel_launch(void* const* d_in, const int* in_sizes, int n_in,
                              void* d_out, int out_size, void* d_ws, size_t ws_size,
                              hipStream_t stream)
{
    (void)in_sizes; (void)n_in; (void)out_size;
    const float* x  = (const float*)d_in[0];
    const float* Wq = (const float*)d_in[1];
    const float* bq = (const float*)d_in[2];
    const float* Wk = (const float*)d_in[3];
    const float* bk = (const float*)d_in[4];
    const float* Wv = (const float*)d_in[5];
    const float* bv = (const float*)d_in[6];
    const float* Wp = (const float*)d_in[7];
    const float* bp = (const float*)d_in[8];

    const int D = 1024, S = 2048, B = 4;
    const int M = B * S; // 8192

    char* p = (char*)d_ws;
    u16* xb   = (u16*)p; p += (size_t)M * D * 2;
    u16* Wcat = (u16*)p; p += (size_t)3 * D * D * 2;
    u16* Wpb  = (u16*)p; p += (size_t)D * D * 2;
    u16* qb   = (u16*)p; p += (size_t)M * D * 2;
    u16* kb   = (u16*)p; p += (size_t)M * D * 2;
    u16* vTb  = (u16*)p; p += (size_t)M * D * 2;   // vT[d][b*S+s], ld=M
    float* sc = (float*)p;                         // scores region
    u16* attnb = xb;                               // alias: x dead after QKV

    const size_t fixed = (size_t)p - (size_t)d_ws;
    const size_t sb1   = (size_t)S * S * 4;
    int zb = (ws_size >= fixed + 4 * sb1) ? 4 : 1;

    hipFuncSetAttribute((const void*)gemm256_qkv,
                        hipFuncAttributeMaxDynamicSharedMemorySize, QLDS);
    hipFuncSetAttribute((const void*)gemm_nt2<0, 0, 1, 0>,
                        hipFuncAttributeMaxDynamicSharedMemorySize, LDS_NT2);
    hipFuncSetAttribute((const void*)gemm_nt2<0, 1, 0, 1>,
                        hipFuncAttributeMaxDynamicSharedMemorySize, LDS_NT2);
    hipFuncSetAttribute((const void*)gemm_nt2<1, 0, 0, 0>,
                        hipFuncAttributeMaxDynamicSharedMemorySize, LDS_NT2);

    // fp32 -> bf16 (2 launches)
    cvt_bf16_kernel<<<(M * D / 4 + 255) / 256, 256, 0, stream>>>(x, xb, M * D / 4);
    cvt_w4_kernel<<<dim3((D * D / 4 + 255) / 256, 4), 256, 0, stream>>>(
        Wq, Wk, Wv, Wp, Wcat, Wpb, D * D / 4);

    // fused QKV (+vT transposed write): [q|k|vT] = x Wcat^T + biases
    gemm256_qkv<<<dim3(3 * D / 256, M / QBM), 512, QLDS, stream>>>(
        xb, Wcat, qb, bq, kb, bk, vTb, bv, M, D, 0.03125f);

    for (int b0 = 0; b0 < B; b0 += zb) {
        // scores = q k^T (lower-triangular tiles only), fp32
        gemm_nt2<0, 0, 1, 0><<<dim3(S / GBN, S / GBM, zb), 512, LDS_NT2, stream>>>(
            qb + (size_t)b0 * S * D, kb + (size_t)b0 * S * D, sc, nullptr,
            S, S, D, D, D, S,
            (long long)S * D, (long long)S * D, (long long)S * S, 1.0f);
        // causal softmax, write P (bf16) in place
        softmax_causal_kernel<<<zb * S, 256, 0, stream>>>(sc, S);
        // attn_out = P v  (A = P bf16 ld 2S; B = vT rows, K causally bounded)
        gemm_nt2<0, 1, 0, 1><<<dim3(D / GBN, S / GBM, zb), 512, LDS_NT2, stream>>>(
            (const u16*)sc, vTb + (size_t)b0 * S, attnb + (size_t)b0 * S * D, nullptr,
            S, D, S, 2 * S, M, D,
            (long long)2 * S * S, (long long)S, (long long)S * D, 1.0f);
    }

    // out = attn_out Wp^T + bp  (fp32 output)
    gemm_nt2<1, 0, 0, 0><<<dim3(D / GBN, M / GBM, 1), 512, LDS_NT2, stream>>>(
        attnb, Wpb, d_out, bp,
        M, D, D, D, D, D, 0, 0, 0, 1.0f);
}

// Round 6
// 202.289 us; speedup vs baseline: 1.1438x; 1.0149x over previous
//
#include <hip/hip_runtime.h>

#define AS1(p) ((const __attribute__((address_space(1))) void*)(p))
#define AS3(p) ((__attribute__((address_space(3))) void*)(p))

typedef unsigned short u16;
typedef __bf16 bf16x8 __attribute__((ext_vector_type(8)));
typedef short s16x8 __attribute__((ext_vector_type(8)));
typedef float f32x4 __attribute__((ext_vector_type(4)));
typedef unsigned short u16x4 __attribute__((ext_vector_type(4)));

__device__ __forceinline__ u16 f2bf(float x) {
    unsigned u = __float_as_uint(x);
    unsigned r = (u + 0x7FFFu + ((u >> 16) & 1u)) >> 16;
    return (u16)r;
}

template <typename V8>
__device__ __forceinline__ auto mfma_sel(V8 a, V8 b, f32x4 c, int)
    -> decltype(__builtin_amdgcn_mfma_f32_16x16x32_bf16(a, b, c, 0, 0, 0))
{
    return __builtin_amdgcn_mfma_f32_16x16x32_bf16(a, b, c, 0, 0, 0);
}
template <typename V8>
__device__ __forceinline__ f32x4 mfma_sel(V8 a, V8 b, f32x4 c, long)
{
    s16x8 a2 = __builtin_bit_cast(s16x8, a);
    s16x8 b2 = __builtin_bit_cast(s16x8, b);
    return __builtin_amdgcn_mfma_f32_16x16x32_bf16(a2, b2, c, 0, 0, 0);
}
__device__ __forceinline__ f32x4 mfma16x16x32(bf16x8 a, bf16x8 b, f32x4 c)
{
    return mfma_sel(a, b, c, 0);
}

// ---------------- fp32 -> bf16 converts ----------------
__global__ __launch_bounds__(256) void cvt_bf16_kernel(const float* __restrict__ in,
                                                       u16* __restrict__ out, int n4)
{
    int i = blockIdx.x * 256 + threadIdx.x;
    if (i >= n4) return;
    float4 f = ((const float4*)in)[i];
    u16x4 o;
    o.x = f2bf(f.x); o.y = f2bf(f.y); o.z = f2bf(f.z); o.w = f2bf(f.w);
    ((u16x4*)out)[i] = o;
}

// all 4 weight matrices in one launch; blockIdx.y selects source/dest
__global__ __launch_bounds__(256) void cvt_w4_kernel(const float* __restrict__ Wq,
                                                     const float* __restrict__ Wk,
                                                     const float* __restrict__ Wv,
                                                     const float* __restrict__ Wp,
                                                     u16* __restrict__ Wcat,
                                                     u16* __restrict__ Wpb, int n4)
{
    int i = blockIdx.x * 256 + threadIdx.x;
    if (i >= n4) return;
    const int by = blockIdx.y;
    const float* src = (by == 0) ? Wq : (by == 1) ? Wk : (by == 2) ? Wv : Wp;
    u16* dst = (by == 3) ? Wpb : (Wcat + (size_t)by * n4 * 4);
    float4 f = ((const float4*)src)[i];
    u16x4 o;
    o.x = f2bf(f.x); o.y = f2bf(f.y); o.z = f2bf(f.z); o.w = f2bf(f.w);
    ((u16x4*)dst)[i] = o;
}

// ============ r3-proven pipelined NT GEMM (128x256, BK=64) ============
// TRIPLE-buffered LDS (144 KB dynamic), 2-tile stage lead, counted vmcnt.
// Race proof: STAGE at iter t writes buf[(t+2)%3] == buf[(t-1)%3], whose last
// reads finished before iter t-1's end barrier. Reads at iter t hit buf[t%3],
// staged at iter t-2 and confirmed by iter t-1's vmcnt(6)+barrier.
// T2 swizzle (rule 21): linear LDS dest, inverse-XOR'd global SOURCE slot,
// XOR'd read: slot16B ^= (row&7).
// BIAS: 0 none, 1 bias[col], 3 fused QKV epilogue (q scaled, k, vT transposed).
#define GBM 128
#define GBN 256
#define GBK 64
#define ABUF 16384           // 128*64*2
#define BBUF 32768           // 256*64*2
#define TBUF (ABUF + BBUF)   // 48 KB per buffer
#define LDS_NT2 (3 * TBUF)   // 147456

template <int BIAS, int OUTBF16, int CSKIP, int CKB>
__global__ __launch_bounds__(512, 2)
void gemm_nt2(const u16* __restrict__ A, const u16* __restrict__ B,
              void* __restrict__ Cv, const float* __restrict__ bias,
              void* __restrict__ C2, const float* __restrict__ bias2,
              void* __restrict__ C3, const float* __restrict__ bias3,
              int M, int N, int K, int lda, int ldb, int ldc,
              long long sA, long long sB, long long sC, float scale)
{
    extern __shared__ char smem[];

    int by = blockIdx.y;
    if (CKB) by = gridDim.y - 1 - by;       // longest-K blocks first
    const int m0 = by * GBM;
    const int n0 = blockIdx.x * GBN;
    if (CSKIP && n0 > m0 + GBM - 1) return;

    const int z = blockIdx.z;
    A += (size_t)z * (size_t)sA;
    B += (size_t)z * (size_t)sB;

    const int t = threadIdx.x;
    const int lane = t & 63;
    const int w = t >> 6;
    const int wr = w >> 2;           // 0..1 (M)
    const int wc = w & 3;            // 0..3 (N)
    const int fr = lane & 15, fg = lane >> 4;

    int Keff = K;
    if (CKB) { Keff = m0 + GBM; if (Keff > K) Keff = K; }
    const int nk = Keff / GBK;

    f32x4 acc[4][4] = {};

    auto STAGE = [&](int kt, int buf) {
        const int k0 = kt * GBK;
        char* sb = smem + buf * TBUF;
        #pragma unroll
        for (int i = 0; i < 2; ++i) {      // A: 128x64 = 1024 16B chunks
            int c = t + i * 512;
            int row = c >> 3;
            int sl = (c & 7) ^ (row & 7);
            __builtin_amdgcn_global_load_lds(
                AS1(A + (size_t)(m0 + row) * lda + k0 + sl * 8),
                AS3(sb + c * 16), 16, 0, 0);
        }
        #pragma unroll
        for (int i = 0; i < 4; ++i) {      // B: 256x64 = 2048 16B chunks
            int c = t + i * 512;
            int row = c >> 3;
            int sl = (c & 7) ^ (row & 7);
            __builtin_amdgcn_global_load_lds(
                AS1(B + (size_t)(n0 + row) * ldb + k0 + sl * 8),
                AS3(sb + ABUF + c * 16), 16, 0, 0);
        }
    };

    STAGE(0, 0);
    STAGE(1, 1);
    asm volatile("s_waitcnt vmcnt(6)" ::: "memory");
    __builtin_amdgcn_s_barrier();

    int cur = 0;
    for (int kt = 0; kt < nk; ++kt) {
        int pb = cur + 2; if (pb >= 3) pb -= 3;
        const bool pf = (kt + 2 < nk);
        if (pf) STAGE(kt + 2, pb);

        const char* la = smem + cur * TBUF;
        const char* lb = la + ABUF;
        #pragma unroll
        for (int kk = 0; kk < GBK; kk += 32) {
            const int cs = (kk >> 3) + fg;
            bf16x8 af[4], bfv[4];
            #pragma unroll
            for (int mi = 0; mi < 4; ++mi) {
                int row = wr * 64 + mi * 16 + fr;
                af[mi] = *(const bf16x8*)(la + (row << 7) + ((cs ^ (row & 7)) << 4));
            }
            #pragma unroll
            for (int ni = 0; ni < 4; ++ni) {
                int row = wc * 64 + ni * 16 + fr;
                bfv[ni] = *(const bf16x8*)(lb + (row << 7) + ((cs ^ (row & 7)) << 4));
            }
            __builtin_amdgcn_s_setprio(1);
            #pragma unroll
            for (int mi = 0; mi < 4; ++mi)
                #pragma unroll
                for (int ni = 0; ni < 4; ++ni)
                    acc[mi][ni] = mfma16x16x32(af[mi], bfv[ni], acc[mi][ni]);
            __builtin_amdgcn_s_setprio(0);
        }

        if (pf) asm volatile("s_waitcnt vmcnt(6)" ::: "memory");
        else    asm volatile("s_waitcnt vmcnt(0)" ::: "memory");
        __builtin_amdgcn_s_barrier();
        ++cur; if (cur >= 3) cur = 0;
    }

    // ---- epilogue: C/D layout col=lane&15, row=(lane>>4)*4+reg ----
    #pragma unroll
    for (int mi = 0; mi < 4; ++mi) {
        #pragma unroll
        for (int ni = 0; ni < 4; ++ni) {
            int col = n0 + wc * 64 + ni * 16 + fr;
            int row0 = m0 + wr * 64 + mi * 16 + fg * 4;
            if (BIAS == 3) {
                // fused QKV: seg 0 -> q (scaled), 1 -> k, 2 -> vT (transposed)
                int seg = col >> 10;
                int ccol = col & 1023;
                if (seg == 0) {
                    float b = bias[ccol];
                    #pragma unroll
                    for (int j = 0; j < 4; ++j)
                        ((u16*)Cv)[(size_t)(row0 + j) * 1024 + ccol] =
                            f2bf((acc[mi][ni][j] + b) * scale);
                } else if (seg == 1) {
                    float b = bias2[ccol];
                    #pragma unroll
                    for (int j = 0; j < 4; ++j)
                        ((u16*)C2)[(size_t)(row0 + j) * 1024 + ccol] =
                            f2bf(acc[mi][ni][j] + b);
                } else {
                    float b = bias3[ccol];
                    u16x4 o;
                    #pragma unroll
                    for (int j = 0; j < 4; ++j) o[j] = f2bf(acc[mi][ni][j] + b);
                    *(u16x4*)&((u16*)C3)[(size_t)ccol * M + row0] = o;  // vT write
                }
            } else {
                float bval = (BIAS == 1) ? bias[col] : 0.f;
                #pragma unroll
                for (int j = 0; j < 4; ++j) {
                    float v = (acc[mi][ni][j] + bval) * scale;
                    size_t off = (size_t)z * (size_t)sC + (size_t)(row0 + j) * ldc + col;
                    if (OUTBF16) ((u16*)Cv)[off] = f2bf(v);
                    else         ((float*)Cv)[off] = v;
                }
            }
        }
    }
}

// ---------------- causal softmax, in-place fp32 -> bf16 P ----------------
__device__ __forceinline__ float waveMax(float v) {
    #pragma unroll
    for (int o = 32; o > 0; o >>= 1) v = fmaxf(v, __shfl_xor(v, o));
    return v;
}
__device__ __forceinline__ float waveSum(float v) {
    #pragma unroll
    for (int o = 32; o > 0; o >>= 1) v += __shfl_xor(v, o);
    return v;
}

__global__ __launch_bounds__(256) void softmax_causal_kernel(float* __restrict__ scores, int S)
{
    __shared__ float red[4];
    const int gb = blockIdx.x;
    const int b = gb / S;
    const int i = gb - b * S;
    float* srow = scores + (size_t)b * S * S + (size_t)i * S;
    u16* prow = (u16*)srow;
    const int t = threadIdx.x;
    const int jlim = ((i >> 7) + 1) << 7;

    float vals[8];
    float mx = -1e30f;
    #pragma unroll
    for (int s = 0; s < 8; ++s) {
        int j = t + (s << 8);
        float x = -1e30f;
        if (j <= i) x = srow[j];
        vals[s] = x;
        mx = fmaxf(mx, x);
    }
    mx = waveMax(mx);
    const int wv = t >> 6;
    if ((t & 63) == 0) red[wv] = mx;
    __syncthreads();
    mx = fmaxf(fmaxf(red[0], red[1]), fmaxf(red[2], red[3]));
    __syncthreads();

    float sum = 0.f;
    #pragma unroll
    for (int s = 0; s < 8; ++s) {
        float e = (vals[s] > -1e29f) ? __expf(vals[s] - mx) : 0.f;
        vals[s] = e;
        sum += e;
    }
    sum = waveSum(sum);
    if ((t & 63) == 0) red[wv] = sum;
    __syncthreads();
    sum = red[0] + red[1] + red[2] + red[3];
    const float inv = 1.f / sum;
    __syncthreads();

    #pragma unroll
    for (int s = 0; s < 8; ++s) {
        int j = t + (s << 8);
        if (j < jlim) prow[j] = f2bf(vals[s] * inv);
    }
}

// ---------------- host launcher ----------------
extern "C" void kernel_launch(void* const* d_in, const int* in_sizes, int n_in,
                              void* d_out, int out_size, void* d_ws, size_t ws_size,
                              hipStream_t stream)
{
    (void)in_sizes; (void)n_in; (void)out_size;
    const float* x  = (const float*)d_in[0];
    const float* Wq = (const float*)d_in[1];
    const float* bq = (const float*)d_in[2];
    const float* Wk = (const float*)d_in[3];
    const float* bk = (const float*)d_in[4];
    const float* Wv = (const float*)d_in[5];
    const float* bv = (const float*)d_in[6];
    const float* Wp = (const float*)d_in[7];
    const float* bp = (const float*)d_in[8];

    const int D = 1024, S = 2048, B = 4;
    const int M = B * S; // 8192

    char* p = (char*)d_ws;
    u16* xb   = (u16*)p; p += (size_t)M * D * 2;   // 16 MB (attnb alias later)
    u16* Wcat = (u16*)p; p += (size_t)3 * D * D * 2;
    u16* Wpb  = (u16*)p; p += (size_t)D * D * 2;
    u16* qb   = (u16*)p; p += (size_t)M * D * 2;
    u16* kb   = (u16*)p; p += (size_t)M * D * 2;
    u16* vTb  = (u16*)p; p += (size_t)M * D * 2;   // vT[d][b*S+s], ld=M
    float* sc = (float*)p;                         // scores region
    u16* attnb = xb;                               // alias: x dead after QKV

    const size_t fixed = (size_t)p - (size_t)d_ws;
    const size_t sb1   = (size_t)S * S * 4;
    int zb = (ws_size >= fixed + 4 * sb1) ? 4
           : (ws_size >= fixed + 2 * sb1) ? 2 : 1;

    hipFuncSetAttribute((const void*)gemm_nt2<3, 1, 0, 0>,
                        hipFuncAttributeMaxDynamicSharedMemorySize, LDS_NT2);
    hipFuncSetAttribute((const void*)gemm_nt2<0, 0, 1, 0>,
                        hipFuncAttributeMaxDynamicSharedMemorySize, LDS_NT2);
    hipFuncSetAttribute((const void*)gemm_nt2<0, 1, 0, 1>,
                        hipFuncAttributeMaxDynamicSharedMemorySize, LDS_NT2);
    hipFuncSetAttribute((const void*)gemm_nt2<1, 0, 0, 0>,
                        hipFuncAttributeMaxDynamicSharedMemorySize, LDS_NT2);

    // fp32 -> bf16 (2 launches)
    cvt_bf16_kernel<<<(M * D / 4 + 255) / 256, 256, 0, stream>>>(x, xb, M * D / 4);
    cvt_w4_kernel<<<dim3((D * D / 4 + 255) / 256, 4), 256, 0, stream>>>(
        Wq, Wk, Wv, Wp, Wcat, Wpb, D * D / 4);

    // fused QKV: [q|k|vT] = x Wcat^T + biases (q scaled, vT transposed write)
    gemm_nt2<3, 1, 0, 0><<<dim3(3 * D / GBN, M / GBM, 1), 512, LDS_NT2, stream>>>(
        xb, Wcat, qb, bq, kb, bk, vTb, bv,
        M, 3 * D, D, D, D, D, 0, 0, 0, 0.03125f);

    for (int b0 = 0; b0 < B; b0 += zb) {
        // scores = q k^T (lower-triangular tiles only), fp32
        gemm_nt2<0, 0, 1, 0><<<dim3(S / GBN, S / GBM, zb), 512, LDS_NT2, stream>>>(
            qb + (size_t)b0 * S * D, kb + (size_t)b0 * S * D, sc, nullptr,
            nullptr, nullptr, nullptr, nullptr,
            S, S, D, D, D, S,
            (long long)S * D, (long long)S * D, (long long)S * S, 1.0f);
        // causal softmax, write P (bf16) in place
        softmax_causal_kernel<<<zb * S, 256, 0, stream>>>(sc, S);
        // attn_out = P v  (A = P bf16 ld 2S; B = vT rows, K causally bounded)
        gemm_nt2<0, 1, 0, 1><<<dim3(D / GBN, S / GBM, zb), 512, LDS_NT2, stream>>>(
            (const u16*)sc, vTb + (size_t)b0 * S, attnb + (size_t)b0 * S * D, nullptr,
            nullptr, nullptr, nullptr, nullptr,
            S, D, S, 2 * S, M, D,
            (long long)2 * S * S, (long long)S, (long long)S * D, 1.0f);
    }

    // out = attn_out Wp^T + bp  (fp32 output)
    gemm_nt2<1, 0, 0, 0><<<dim3(D / GBN, M / GBM, 1), 512, LDS_NT2, stream>>>(
        attnb, Wpb, d_out, bp, nullptr, nullptr, nullptr, nullptr,
        M, D, D, D, D, D, 0, 0, 0, 1.0f);
}

// Round 7
// 200.661 us; speedup vs baseline: 1.1531x; 1.0081x over previous
//
#include <hip/hip_runtime.h>

#define AS1(p) ((const __attribute__((address_space(1))) void*)(p))
#define AS3(p) ((__attribute__((address_space(3))) void*)(p))

typedef unsigned short u16;
typedef __bf16 bf16x8 __attribute__((ext_vector_type(8)));
typedef short s16x8 __attribute__((ext_vector_type(8)));
typedef float f32x4 __attribute__((ext_vector_type(4)));
typedef unsigned short u16x4 __attribute__((ext_vector_type(4)));
typedef unsigned short u16x8v __attribute__((ext_vector_type(8)));

__device__ __forceinline__ u16 f2bf(float x) {
    unsigned u = __float_as_uint(x);
    unsigned r = (u + 0x7FFFu + ((u >> 16) & 1u)) >> 16;
    return (u16)r;
}
__device__ __forceinline__ float bf2f(u16 x) {
    return __uint_as_float(((unsigned)x) << 16);
}

template <typename V8>
__device__ __forceinline__ auto mfma_sel(V8 a, V8 b, f32x4 c, int)
    -> decltype(__builtin_amdgcn_mfma_f32_16x16x32_bf16(a, b, c, 0, 0, 0))
{
    return __builtin_amdgcn_mfma_f32_16x16x32_bf16(a, b, c, 0, 0, 0);
}
template <typename V8>
__device__ __forceinline__ f32x4 mfma_sel(V8 a, V8 b, f32x4 c, long)
{
    s16x8 a2 = __builtin_bit_cast(s16x8, a);
    s16x8 b2 = __builtin_bit_cast(s16x8, b);
    return __builtin_amdgcn_mfma_f32_16x16x32_bf16(a2, b2, c, 0, 0, 0);
}
__device__ __forceinline__ f32x4 mfma16x16x32(bf16x8 a, bf16x8 b, f32x4 c)
{
    return mfma_sel(a, b, c, 0);
}

// ---------------- fp32 -> bf16 converts ----------------
__global__ __launch_bounds__(256) void cvt_bf16_kernel(const float* __restrict__ in,
                                                       u16* __restrict__ out, int n4)
{
    int i = blockIdx.x * 256 + threadIdx.x;
    if (i >= n4) return;
    float4 f = ((const float4*)in)[i];
    u16x4 o;
    o.x = f2bf(f.x); o.y = f2bf(f.y); o.z = f2bf(f.z); o.w = f2bf(f.w);
    ((u16x4*)out)[i] = o;
}

__global__ __launch_bounds__(256) void cvt_w4_kernel(const float* __restrict__ Wq,
                                                     const float* __restrict__ Wk,
                                                     const float* __restrict__ Wv,
                                                     const float* __restrict__ Wp,
                                                     u16* __restrict__ Wcat,
                                                     u16* __restrict__ Wpb, int n4)
{
    int i = blockIdx.x * 256 + threadIdx.x;
    if (i >= n4) return;
    const int by = blockIdx.y;
    const float* src = (by == 0) ? Wq : (by == 1) ? Wk : (by == 2) ? Wv : Wp;
    u16* dst = (by == 3) ? Wpb : (Wcat + (size_t)by * n4 * 4);
    float4 f = ((const float4*)src)[i];
    u16x4 o;
    o.x = f2bf(f.x); o.y = f2bf(f.y); o.z = f2bf(f.z); o.w = f2bf(f.w);
    ((u16x4*)dst)[i] = o;
}

// ---------------- bf16 transpose: in[R][C] -> out[C][R], 64x64 tiles ----------------
__global__ __launch_bounds__(256) void transpose16(const u16* __restrict__ in,
                                                   u16* __restrict__ out, int R, int C)
{
    __shared__ u16 tl[64][65];
    const int tr0 = blockIdx.y * 64, tc0 = blockIdx.x * 64;
    const int t = threadIdx.x;
    const int r = t >> 2, c4 = (t & 3) << 4;

    const u16* src = in + (size_t)(tr0 + r) * C + tc0 + c4;
    u16x8v a0 = *(const u16x8v*)src;
    u16x8v a1 = *(const u16x8v*)(src + 8);
    #pragma unroll
    for (int j = 0; j < 8; ++j) { tl[r][c4 + j] = a0[j]; tl[r][c4 + 8 + j] = a1[j]; }
    __syncthreads();

    u16x8v b0, b1;
    #pragma unroll
    for (int j = 0; j < 8; ++j) { b0[j] = tl[c4 + j][r]; b1[j] = tl[c4 + 8 + j][r]; }
    u16* dst = out + (size_t)(tc0 + r) * R + tr0 + c4;
    *(u16x8v*)dst = b0;
    *(u16x8v*)(dst + 8) = b1;
}

// ============ r3-proven pipelined NT GEMM (128x256, BK=64) ============
// TRIPLE-buffered LDS (144 KB dynamic), 2-tile stage lead, counted vmcnt.
// Race proof: STAGE at iter t writes buf[(t+2)%3] == buf[(t-1)%3], whose last
// reads finished before iter t-1's end barrier. Reads at iter t hit buf[t%3],
// staged at iter t-2 and confirmed by iter t-1's vmcnt(6)+barrier.
// T2 swizzle (rule 21): linear LDS dest, inverse-XOR'd global SOURCE slot,
// XOR'd read: slot16B ^= (row&7).
// BIAS: 0 none, 1 bias[col], 3 fused QKV epilogue (q scaled / k / v, row-major).
#define GBM 128
#define GBN 256
#define GBK 64
#define ABUF 16384           // 128*64*2
#define BBUF 32768           // 256*64*2
#define TBUF (ABUF + BBUF)   // 48 KB per buffer
#define LDS_NT2 (3 * TBUF)   // 147456

template <int BIAS, int OUTBF16, int CSKIP, int CKB>
__global__ __launch_bounds__(512, 2)
void gemm_nt2(const u16* __restrict__ A, const u16* __restrict__ B,
              void* __restrict__ Cv, const float* __restrict__ bias,
              void* __restrict__ C2, const float* __restrict__ bias2,
              void* __restrict__ C3, const float* __restrict__ bias3,
              int M, int N, int K, int lda, int ldb, int ldc,
              long long sA, long long sB, long long sC, float scale)
{
    extern __shared__ char smem[];

    int by = blockIdx.y;
    if (CKB) by = gridDim.y - 1 - by;       // longest-K blocks first
    const int m0 = by * GBM;
    const int n0 = blockIdx.x * GBN;
    if (CSKIP && n0 > m0 + GBM - 1) return;

    const int z = blockIdx.z;
    A += (size_t)z * (size_t)sA;
    B += (size_t)z * (size_t)sB;

    const int t = threadIdx.x;
    const int lane = t & 63;
    const int w = t >> 6;
    const int wr = w >> 2;           // 0..1 (M)
    const int wc = w & 3;            // 0..3 (N)
    const int fr = lane & 15, fg = lane >> 4;

    int Keff = K;
    if (CKB) { Keff = m0 + GBM; if (Keff > K) Keff = K; }
    const int nk = Keff / GBK;

    f32x4 acc[4][4] = {};

    auto STAGE = [&](int kt, int buf) {
        const int k0 = kt * GBK;
        char* sb = smem + buf * TBUF;
        #pragma unroll
        for (int i = 0; i < 2; ++i) {      // A: 128x64 = 1024 16B chunks
            int c = t + i * 512;
            int row = c >> 3;
            int sl = (c & 7) ^ (row & 7);
            __builtin_amdgcn_global_load_lds(
                AS1(A + (size_t)(m0 + row) * lda + k0 + sl * 8),
                AS3(sb + c * 16), 16, 0, 0);
        }
        #pragma unroll
        for (int i = 0; i < 4; ++i) {      // B: 256x64 = 2048 16B chunks
            int c = t + i * 512;
            int row = c >> 3;
            int sl = (c & 7) ^ (row & 7);
            __builtin_amdgcn_global_load_lds(
                AS1(B + (size_t)(n0 + row) * ldb + k0 + sl * 8),
                AS3(sb + ABUF + c * 16), 16, 0, 0);
        }
    };

    STAGE(0, 0);
    STAGE(1, 1);
    asm volatile("s_waitcnt vmcnt(6)" ::: "memory");
    __builtin_amdgcn_s_barrier();

    int cur = 0;
    for (int kt = 0; kt < nk; ++kt) {
        int pb = cur + 2; if (pb >= 3) pb -= 3;
        const bool pf = (kt + 2 < nk);
        if (pf) STAGE(kt + 2, pb);

        const char* la = smem + cur * TBUF;
        const char* lb = la + ABUF;
        #pragma unroll
        for (int kk = 0; kk < GBK; kk += 32) {
            const int cs = (kk >> 3) + fg;
            bf16x8 af[4], bfv[4];
            #pragma unroll
            for (int mi = 0; mi < 4; ++mi) {
                int row = wr * 64 + mi * 16 + fr;
                af[mi] = *(const bf16x8*)(la + (row << 7) + ((cs ^ (row & 7)) << 4));
            }
            #pragma unroll
            for (int ni = 0; ni < 4; ++ni) {
                int row = wc * 64 + ni * 16 + fr;
                bfv[ni] = *(const bf16x8*)(lb + (row << 7) + ((cs ^ (row & 7)) << 4));
            }
            __builtin_amdgcn_s_setprio(1);
            #pragma unroll
            for (int mi = 0; mi < 4; ++mi)
                #pragma unroll
                for (int ni = 0; ni < 4; ++ni)
                    acc[mi][ni] = mfma16x16x32(af[mi], bfv[ni], acc[mi][ni]);
            __builtin_amdgcn_s_setprio(0);
        }

        if (pf) asm volatile("s_waitcnt vmcnt(6)" ::: "memory");
        else    asm volatile("s_waitcnt vmcnt(0)" ::: "memory");
        __builtin_amdgcn_s_barrier();
        ++cur; if (cur >= 3) cur = 0;
    }

    // ---- epilogue: C/D layout col=lane&15, row=(lane>>4)*4+reg ----
    #pragma unroll
    for (int mi = 0; mi < 4; ++mi) {
        #pragma unroll
        for (int ni = 0; ni < 4; ++ni) {
            int col = n0 + wc * 64 + ni * 16 + fr;
            int row0 = m0 + wr * 64 + mi * 16 + fg * 4;
            if (BIAS == 3) {
                // fused QKV: seg 0 -> q (scaled), 1 -> k, 2 -> v (all row-major)
                int seg = col >> 10;
                int ccol = col & 1023;
                u16* dst = (seg == 0) ? (u16*)Cv : (seg == 1) ? (u16*)C2 : (u16*)C3;
                float b = ((seg == 0) ? bias : (seg == 1) ? bias2 : bias3)[ccol];
                float sc_ = (seg == 0) ? scale : 1.f;
                #pragma unroll
                for (int j = 0; j < 4; ++j)
                    dst[(size_t)(row0 + j) * 1024 + ccol] =
                        f2bf((acc[mi][ni][j] + b) * sc_);
            } else {
                float bval = (BIAS == 1) ? bias[col] : 0.f;
                #pragma unroll
                for (int j = 0; j < 4; ++j) {
                    float v = (acc[mi][ni][j] + bval) * scale;
                    size_t off = (size_t)z * (size_t)sC + (size_t)(row0 + j) * ldc + col;
                    if (OUTBF16) ((u16*)Cv)[off] = f2bf(v);
                    else         ((float*)Cv)[off] = v;
                }
            }
        }
    }
}

// ---------------- causal softmax on bf16 scores, in place ----------------
// One block per row; 256 threads x u16x8 chunk each (S=2048 exactly).
__device__ __forceinline__ float waveMax(float v) {
    #pragma unroll
    for (int o = 32; o > 0; o >>= 1) v = fmaxf(v, __shfl_xor(v, o));
    return v;
}
__device__ __forceinline__ float waveSum(float v) {
    #pragma unroll
    for (int o = 32; o > 0; o >>= 1) v += __shfl_xor(v, o);
    return v;
}

__global__ __launch_bounds__(256) void softmax_causal_bf16(u16* __restrict__ scores, int S)
{
    __shared__ float red[4];
    const int gb = blockIdx.x;
    const int b = gb / S;
    const int i = gb - b * S;
    u16* row = scores + (size_t)b * S * S + (size_t)i * S;
    const int t = threadIdx.x;
    const int jlim = ((i >> 7) + 1) << 7;   // computed-region end (tile-rounded)
    const int j0 = t << 3;
    const bool act = j0 < jlim;             // chunk inside computed region

    float v[8];
    float mx = -1e30f;
    if (act) {
        u16x8v raw = *(const u16x8v*)(row + j0);
        #pragma unroll
        for (int e = 0; e < 8; ++e) {
            float x = bf2f(raw[e]);
            v[e] = (j0 + e <= i) ? x : -1e30f;
            mx = fmaxf(mx, v[e]);
        }
    } else {
        #pragma unroll
        for (int e = 0; e < 8; ++e) v[e] = -1e30f;
    }

    mx = waveMax(mx);
    const int wv = t >> 6;
    if ((t & 63) == 0) red[wv] = mx;
    __syncthreads();
    mx = fmaxf(fmaxf(red[0], red[1]), fmaxf(red[2], red[3]));
    __syncthreads();

    float sum = 0.f;
    if (act) {
        #pragma unroll
        for (int e = 0; e < 8; ++e) {
            float ex = (v[e] > -1e29f) ? __expf(v[e] - mx) : 0.f;
            v[e] = ex;
            sum += ex;
        }
    }
    sum = waveSum(sum);
    if ((t & 63) == 0) red[wv] = sum;
    __syncthreads();
    sum = red[0] + red[1] + red[2] + red[3];
    const float inv = 1.f / sum;

    if (act) {
        u16x8v o;
        #pragma unroll
        for (int e = 0; e < 8; ++e) o[e] = f2bf(v[e] * inv);
        *(u16x8v*)(row + j0) = o;           // each thread rewrites only its chunk
    }
}

// ---------------- host launcher ----------------
extern "C" void kernel_launch(void* const* d_in, const int* in_sizes, int n_in,
                              void* d_out, int out_size, void* d_ws, size_t ws_size,
                              hipStream_t stream)
{
    (void)in_sizes; (void)n_in; (void)out_size;
    const float* x  = (const float*)d_in[0];
    const float* Wq = (const float*)d_in[1];
    const float* bq = (const float*)d_in[2];
    const float* Wk = (const float*)d_in[3];
    const float* bk = (const float*)d_in[4];
    const float* Wv = (const float*)d_in[5];
    const float* bv = (const float*)d_in[6];
    const float* Wp = (const float*)d_in[7];
    const float* bp = (const float*)d_in[8];

    const int D = 1024, S = 2048, B = 4;
    const int M = B * S; // 8192

    char* p = (char*)d_ws;
    u16* xb   = (u16*)p; p += (size_t)M * D * 2;   // 16 MB (attnb alias later)
    u16* Wcat = (u16*)p; p += (size_t)3 * D * D * 2;
    u16* Wpb  = (u16*)p; p += (size_t)D * D * 2;
    u16* qb   = (u16*)p; p += (size_t)M * D * 2;
    u16* kb   = (u16*)p; p += (size_t)M * D * 2;
    u16* vTb  = (u16*)p; p += (size_t)M * D * 2;   // vT[d][b*S+s], ld=M
    u16* vb   = (u16*)p;                           // dead after transpose
    u16* sc   = (u16*)p;                           // bf16 scores (overlaps vb)
    u16* attnb = xb;                               // alias: x dead after QKV

    const size_t fixed = (size_t)p - (size_t)d_ws;
    const size_t sb1   = (size_t)S * S * 2;        // bf16 scores per batch
    const size_t vbsz  = (size_t)M * D * 2;
    int zb = (ws_size >= fixed + (4 * sb1 > vbsz ? 4 * sb1 : vbsz)) ? 4
           : (ws_size >= fixed + (2 * sb1 > vbsz ? 2 * sb1 : vbsz)) ? 2 : 1;

    hipFuncSetAttribute((const void*)gemm_nt2<3, 1, 0, 0>,
                        hipFuncAttributeMaxDynamicSharedMemorySize, LDS_NT2);
    hipFuncSetAttribute((const void*)gemm_nt2<0, 1, 1, 0>,
                        hipFuncAttributeMaxDynamicSharedMemorySize, LDS_NT2);
    hipFuncSetAttribute((const void*)gemm_nt2<0, 1, 0, 1>,
                        hipFuncAttributeMaxDynamicSharedMemorySize, LDS_NT2);
    hipFuncSetAttribute((const void*)gemm_nt2<1, 0, 0, 0>,
                        hipFuncAttributeMaxDynamicSharedMemorySize, LDS_NT2);

    // fp32 -> bf16
    cvt_bf16_kernel<<<(M * D / 4 + 255) / 256, 256, 0, stream>>>(x, xb, M * D / 4);
    cvt_w4_kernel<<<dim3((D * D / 4 + 255) / 256, 4), 256, 0, stream>>>(
        Wq, Wk, Wv, Wp, Wcat, Wpb, D * D / 4);

    // fused QKV: [q|k|v] = x Wcat^T + biases (q scaled); all row-major
    gemm_nt2<3, 1, 0, 0><<<dim3(3 * D / GBN, M / GBM, 1), 512, LDS_NT2, stream>>>(
        xb, Wcat, qb, bq, kb, bk, vb, bv,
        M, 3 * D, D, D, D, D, 0, 0, 0, 0.03125f);

    // vT = v^T (proven 64x64-tile LDS transpose)
    transpose16<<<dim3(D / 64, M / 64), 256, 0, stream>>>(vb, vTb, M, D);

    for (int b0 = 0; b0 < B; b0 += zb) {
        // scores = q k^T (lower-triangular tiles only), bf16 out
        gemm_nt2<0, 1, 1, 0><<<dim3(S / GBN, S / GBM, zb), 512, LDS_NT2, stream>>>(
            qb + (size_t)b0 * S * D, kb + (size_t)b0 * S * D, sc, nullptr,
            nullptr, nullptr, nullptr, nullptr,
            S, S, D, D, D, S,
            (long long)S * D, (long long)S * D, (long long)S * S, 1.0f);
        // causal softmax in place (bf16 -> bf16 P)
        softmax_causal_bf16<<<zb * S, 256, 0, stream>>>(sc, S);
        // attn_out = P v  (A = P bf16 ld S; B = vT rows, K causally bounded)
        gemm_nt2<0, 1, 0, 1><<<dim3(D / GBN, S / GBM, zb), 512, LDS_NT2, stream>>>(
            sc, vTb + (size_t)b0 * S, attnb + (size_t)b0 * S * D, nullptr,
            nullptr, nullptr, nullptr, nullptr,
            S, D, S, S, M, D,
            (long long)S * S, (long long)S, (long long)S * D, 1.0f);
    }

    // out = attn_out Wp^T + bp  (fp32 output)
    gemm_nt2<1, 0, 0, 0><<<dim3(D / GBN, M / GBM, 1), 512, LDS_NT2, stream>>>(
        attnb, Wpb, d_out, bp, nullptr, nullptr, nullptr, nullptr,
        M, D, D, D, D, D, 0, 0, 0, 1.0f);
}

// Round 8
// 200.181 us; speedup vs baseline: 1.1559x; 1.0024x over previous
//
#include <hip/hip_runtime.h>

#define AS1(p) ((const __attribute__((address_space(1))) void*)(p))
#define AS3(p) ((__attribute__((address_space(3))) void*)(p))

typedef unsigned short u16;
typedef __bf16 bf16x8 __attribute__((ext_vector_type(8)));
typedef short s16x8 __attribute__((ext_vector_type(8)));
typedef float f32x4 __attribute__((ext_vector_type(4)));
typedef unsigned short u16x4 __attribute__((ext_vector_type(4)));
typedef unsigned short u16x8v __attribute__((ext_vector_type(8)));

__device__ __forceinline__ u16 f2bf(float x) {
    unsigned u = __float_as_uint(x);
    unsigned r = (u + 0x7FFFu + ((u >> 16) & 1u)) >> 16;
    return (u16)r;
}
__device__ __forceinline__ float bf2f(u16 x) {
    return __uint_as_float(((unsigned)x) << 16);
}

template <typename V8>
__device__ __forceinline__ auto mfma_sel(V8 a, V8 b, f32x4 c, int)
    -> decltype(__builtin_amdgcn_mfma_f32_16x16x32_bf16(a, b, c, 0, 0, 0))
{
    return __builtin_amdgcn_mfma_f32_16x16x32_bf16(a, b, c, 0, 0, 0);
}
template <typename V8>
__device__ __forceinline__ f32x4 mfma_sel(V8 a, V8 b, f32x4 c, long)
{
    s16x8 a2 = __builtin_bit_cast(s16x8, a);
    s16x8 b2 = __builtin_bit_cast(s16x8, b);
    return __builtin_amdgcn_mfma_f32_16x16x32_bf16(a2, b2, c, 0, 0, 0);
}
__device__ __forceinline__ f32x4 mfma16x16x32(bf16x8 a, bf16x8 b, f32x4 c)
{
    return mfma_sel(a, b, c, 0);
}

// ---------------- fp32 -> bf16 converts ----------------
__global__ __launch_bounds__(256) void cvt_bf16_kernel(const float* __restrict__ in,
                                                       u16* __restrict__ out, int n4)
{
    int i = blockIdx.x * 256 + threadIdx.x;
    if (i >= n4) return;
    float4 f = ((const float4*)in)[i];
    u16x4 o;
    o.x = f2bf(f.x); o.y = f2bf(f.y); o.z = f2bf(f.z); o.w = f2bf(f.w);
    ((u16x4*)out)[i] = o;
}

__global__ __launch_bounds__(256) void cvt_w4_kernel(const float* __restrict__ Wq,
                                                     const float* __restrict__ Wk,
                                                     const float* __restrict__ Wv,
                                                     const float* __restrict__ Wp,
                                                     u16* __restrict__ Wcat,
                                                     u16* __restrict__ Wpb, int n4)
{
    int i = blockIdx.x * 256 + threadIdx.x;
    if (i >= n4) return;
    const int by = blockIdx.y;
    const float* src = (by == 0) ? Wq : (by == 1) ? Wk : (by == 2) ? Wv : Wp;
    u16* dst = (by == 3) ? Wpb : (Wcat + (size_t)by * n4 * 4);
    float4 f = ((const float4*)src)[i];
    u16x4 o;
    o.x = f2bf(f.x); o.y = f2bf(f.y); o.z = f2bf(f.z); o.w = f2bf(f.w);
    ((u16x4*)dst)[i] = o;
}

// ---------------- bf16 transpose: in[R][C] -> out[C][R], 64x64 tiles ----------------
__global__ __launch_bounds__(256) void transpose16(const u16* __restrict__ in,
                                                   u16* __restrict__ out, int R, int C)
{
    __shared__ u16 tl[64][65];
    const int tr0 = blockIdx.y * 64, tc0 = blockIdx.x * 64;
    const int t = threadIdx.x;
    const int r = t >> 2, c4 = (t & 3) << 4;

    const u16* src = in + (size_t)(tr0 + r) * C + tc0 + c4;
    u16x8v a0 = *(const u16x8v*)src;
    u16x8v a1 = *(const u16x8v*)(src + 8);
    #pragma unroll
    for (int j = 0; j < 8; ++j) { tl[r][c4 + j] = a0[j]; tl[r][c4 + 8 + j] = a1[j]; }
    __syncthreads();

    u16x8v b0, b1;
    #pragma unroll
    for (int j = 0; j < 8; ++j) { b0[j] = tl[c4 + j][r]; b1[j] = tl[c4 + 8 + j][r]; }
    u16* dst = out + (size_t)(tc0 + r) * R + tr0 + c4;
    *(u16x8v*)dst = b0;
    *(u16x8v*)(dst + 8) = b1;
}

// ============ 256x256 2-phase pipelined NT GEMM (BK=64, dbuf) ============
// 8 waves 2Mx4N, per-wave 128x64 out (acc 8x4 f32x4 = 128 VGPR).
// LDS: 2 buffers x (A 32K + B 32K) = 128 KB. Per K-tile: 2 phases (kk=0,32);
// phase = {12 ds_read_b128 (8 A-frag + 4 B-frag) ; [ph0: stage FULL next
// tile, 8 global_load_lds] ; barrier ; lgkmcnt(0) ; setprio(1) ; 32 MFMA ;
// setprio(0) ; barrier}. vmcnt(0) only at tile end.
// Race proof: stages at tile t write buf^1, whose last readers (tile t-1,
// phase 1) all executed lgkmcnt(0) before tile t-1's end barrier. Reads of
// buf^1 at tile t+1 are guarded by tile t's end vmcnt(0)+barrier. Stage
// loads issue in phase 0 => ~1.5 phases (>=1200 cyc) of MFMA cover before
// the tile-end vmcnt(0).
// T2 swizzle (rule 21): linear LDS dest, inverse-XOR'd global SOURCE slot,
// XOR'd read: slot16B ^= (row&7).
#define HBM 256
#define HBN 256
#define HBK 64
#define HABUF 32768            // 256*64*2
#define HTBUF 65536            // A+B per buffer
#define LDS_256 131072         // 2 buffers

template <int BIAS, int OUTBF16, int CSKIP>
__global__ __launch_bounds__(512, 2)
void gemm256(const u16* __restrict__ A, const u16* __restrict__ B,
             void* __restrict__ Cv, const float* __restrict__ bias,
             void* __restrict__ C2, const float* __restrict__ bias2,
             void* __restrict__ C3, const float* __restrict__ bias3,
             int M, int N, int K, int lda, int ldb, int ldc,
             long long sA, long long sB, long long sC, float scale)
{
    extern __shared__ char smem[];

    const int m0 = blockIdx.y * HBM;
    const int n0 = blockIdx.x * HBN;
    if (CSKIP && n0 > m0 + HBM - 1) return;

    const int z = blockIdx.z;
    A += (size_t)z * (size_t)sA;
    B += (size_t)z * (size_t)sB;

    const int t = threadIdx.x;
    const int lane = t & 63;
    const int w = t >> 6;
    const int wr = w >> 2;           // 0..1 (M)
    const int wc = w & 3;            // 0..3 (N)
    const int fr = lane & 15, fg = lane >> 4;

    const int nk = K / HBK;

    f32x4 acc[8][4] = {};

    auto STAGE = [&](int kt, int buf) {
        const int k0 = kt * HBK;
        char* sb = smem + buf * HTBUF;
        #pragma unroll
        for (int i = 0; i < 4; ++i) {      // A: 256x64 = 2048 16B chunks
            int c = t + i * 512;
            int row = c >> 3;
            int sl = (c & 7) ^ (row & 7);
            __builtin_amdgcn_global_load_lds(
                AS1(A + (size_t)(m0 + row) * lda + k0 + sl * 8),
                AS3(sb + c * 16), 16, 0, 0);
        }
        #pragma unroll
        for (int i = 0; i < 4; ++i) {      // B: 256x64
            int c = t + i * 512;
            int row = c >> 3;
            int sl = (c & 7) ^ (row & 7);
            __builtin_amdgcn_global_load_lds(
                AS1(B + (size_t)(n0 + row) * ldb + k0 + sl * 8),
                AS3(sb + HABUF + c * 16), 16, 0, 0);
        }
    };

    STAGE(0, 0);
    asm volatile("s_waitcnt vmcnt(0)" ::: "memory");
    __builtin_amdgcn_s_barrier();

    int cur = 0;
    for (int kt = 0; kt < nk; ++kt) {
        const char* la = smem + cur * HTBUF;
        const char* lb = la + HABUF;
        const bool pf = (kt + 1 < nk);

        #pragma unroll
        for (int kk = 0; kk < HBK; kk += 32) {   // 2 phases per K-tile
            const int cs = (kk >> 3) + fg;       // column 16B-slot
            bf16x8 af[8], bfv[4];
            #pragma unroll
            for (int mi = 0; mi < 8; ++mi) {
                int row = wr * 128 + mi * 16 + fr;
                af[mi] = *(const bf16x8*)(la + (row << 7) + ((cs ^ (row & 7)) << 4));
            }
            #pragma unroll
            for (int ni = 0; ni < 4; ++ni) {
                int row = wc * 64 + ni * 16 + fr;
                bfv[ni] = *(const bf16x8*)(lb + (row << 7) + ((cs ^ (row & 7)) << 4));
            }
            if (kk == 0 && pf) STAGE(kt + 1, cur ^ 1);  // full next-tile burst

            __builtin_amdgcn_s_barrier();
            asm volatile("s_waitcnt lgkmcnt(0)" ::: "memory");
            __builtin_amdgcn_s_setprio(1);
            #pragma unroll
            for (int mi = 0; mi < 8; ++mi)
                #pragma unroll
                for (int ni = 0; ni < 4; ++ni)
                    acc[mi][ni] = mfma16x16x32(af[mi], bfv[ni], acc[mi][ni]);
            __builtin_amdgcn_s_setprio(0);
            if (kk == 32)                         // tile end: next buf staged
                asm volatile("s_waitcnt vmcnt(0)" ::: "memory");
            __builtin_amdgcn_s_barrier();
        }
        cur ^= 1;
    }

    // ---- epilogue: C/D layout col=lane&15, row=(lane>>4)*4+reg ----
    #pragma unroll
    for (int mi = 0; mi < 8; ++mi) {
        #pragma unroll
        for (int ni = 0; ni < 4; ++ni) {
            int col = n0 + wc * 64 + ni * 16 + fr;
            int row0 = m0 + wr * 128 + mi * 16 + fg * 4;
            if (BIAS == 3) {
                int seg = col >> 10;
                int ccol = col & 1023;
                u16* dst = (seg == 0) ? (u16*)Cv : (seg == 1) ? (u16*)C2 : (u16*)C3;
                float b = ((seg == 0) ? bias : (seg == 1) ? bias2 : bias3)[ccol];
                float sc_ = (seg == 0) ? scale : 1.f;
                #pragma unroll
                for (int j = 0; j < 4; ++j)
                    dst[(size_t)(row0 + j) * 1024 + ccol] =
                        f2bf((acc[mi][ni][j] + b) * sc_);
            } else {
                float bval = (BIAS == 1) ? bias[col] : 0.f;
                #pragma unroll
                for (int j = 0; j < 4; ++j) {
                    float v = (acc[mi][ni][j] + bval) * scale;
                    size_t off = (size_t)z * (size_t)sC + (size_t)(row0 + j) * ldc + col;
                    if (OUTBF16) ((u16*)Cv)[off] = f2bf(v);
                    else         ((float*)Cv)[off] = v;
                }
            }
        }
    }
}

// ============ r3-proven pipelined NT GEMM (128x256, BK=64) ============
// (kept for PV and proj; see r3 notes for invariants)
#define GBM 128
#define GBN 256
#define GBK 64
#define ABUF 16384
#define BBUF 32768
#define TBUF (ABUF + BBUF)
#define LDS_NT2 (3 * TBUF)

template <int BIAS, int OUTBF16, int CSKIP, int CKB>
__global__ __launch_bounds__(512, 2)
void gemm_nt2(const u16* __restrict__ A, const u16* __restrict__ B,
              void* __restrict__ Cv, const float* __restrict__ bias,
              int M, int N, int K, int lda, int ldb, int ldc,
              long long sA, long long sB, long long sC, float scale)
{
    extern __shared__ char smem[];

    int by = blockIdx.y;
    if (CKB) by = gridDim.y - 1 - by;
    const int m0 = by * GBM;
    const int n0 = blockIdx.x * GBN;
    if (CSKIP && n0 > m0 + GBM - 1) return;

    const int z = blockIdx.z;
    A += (size_t)z * (size_t)sA;
    B += (size_t)z * (size_t)sB;

    const int t = threadIdx.x;
    const int lane = t & 63;
    const int w = t >> 6;
    const int wr = w >> 2;
    const int wc = w & 3;
    const int fr = lane & 15, fg = lane >> 4;

    int Keff = K;
    if (CKB) { Keff = m0 + GBM; if (Keff > K) Keff = K; }
    const int nk = Keff / GBK;

    f32x4 acc[4][4] = {};

    auto STAGE = [&](int kt, int buf) {
        const int k0 = kt * GBK;
        char* sb = smem + buf * TBUF;
        #pragma unroll
        for (int i = 0; i < 2; ++i) {
            int c = t + i * 512;
            int row = c >> 3;
            int sl = (c & 7) ^ (row & 7);
            __builtin_amdgcn_global_load_lds(
                AS1(A + (size_t)(m0 + row) * lda + k0 + sl * 8),
                AS3(sb + c * 16), 16, 0, 0);
        }
        #pragma unroll
        for (int i = 0; i < 4; ++i) {
            int c = t + i * 512;
            int row = c >> 3;
            int sl = (c & 7) ^ (row & 7);
            __builtin_amdgcn_global_load_lds(
                AS1(B + (size_t)(n0 + row) * ldb + k0 + sl * 8),
                AS3(sb + ABUF + c * 16), 16, 0, 0);
        }
    };

    STAGE(0, 0);
    STAGE(1, 1);
    asm volatile("s_waitcnt vmcnt(6)" ::: "memory");
    __builtin_amdgcn_s_barrier();

    int cur = 0;
    for (int kt = 0; kt < nk; ++kt) {
        int pb = cur + 2; if (pb >= 3) pb -= 3;
        const bool pf = (kt + 2 < nk);
        if (pf) STAGE(kt + 2, pb);

        const char* la = smem + cur * TBUF;
        const char* lb = la + ABUF;
        #pragma unroll
        for (int kk = 0; kk < GBK; kk += 32) {
            const int cs = (kk >> 3) + fg;
            bf16x8 af[4], bfv[4];
            #pragma unroll
            for (int mi = 0; mi < 4; ++mi) {
                int row = wr * 64 + mi * 16 + fr;
                af[mi] = *(const bf16x8*)(la + (row << 7) + ((cs ^ (row & 7)) << 4));
            }
            #pragma unroll
            for (int ni = 0; ni < 4; ++ni) {
                int row = wc * 64 + ni * 16 + fr;
                bfv[ni] = *(const bf16x8*)(lb + (row << 7) + ((cs ^ (row & 7)) << 4));
            }
            __builtin_amdgcn_s_setprio(1);
            #pragma unroll
            for (int mi = 0; mi < 4; ++mi)
                #pragma unroll
                for (int ni = 0; ni < 4; ++ni)
                    acc[mi][ni] = mfma16x16x32(af[mi], bfv[ni], acc[mi][ni]);
            __builtin_amdgcn_s_setprio(0);
        }

        if (pf) asm volatile("s_waitcnt vmcnt(6)" ::: "memory");
        else    asm volatile("s_waitcnt vmcnt(0)" ::: "memory");
        __builtin_amdgcn_s_barrier();
        ++cur; if (cur >= 3) cur = 0;
    }

    #pragma unroll
    for (int mi = 0; mi < 4; ++mi) {
        #pragma unroll
        for (int ni = 0; ni < 4; ++ni) {
            int col = n0 + wc * 64 + ni * 16 + fr;
            int row0 = m0 + wr * 64 + mi * 16 + fg * 4;
            float bval = (BIAS == 1) ? bias[col] : 0.f;
            #pragma unroll
            for (int j = 0; j < 4; ++j) {
                float v = (acc[mi][ni][j] + bval) * scale;
                size_t off = (size_t)z * (size_t)sC + (size_t)(row0 + j) * ldc + col;
                if (OUTBF16) ((u16*)Cv)[off] = f2bf(v);
                else         ((float*)Cv)[off] = v;
            }
        }
    }
}

// ---------------- causal softmax on bf16 scores, in place ----------------
__device__ __forceinline__ float waveMax(float v) {
    #pragma unroll
    for (int o = 32; o > 0; o >>= 1) v = fmaxf(v, __shfl_xor(v, o));
    return v;
}
__device__ __forceinline__ float waveSum(float v) {
    #pragma unroll
    for (int o = 32; o > 0; o >>= 1) v += __shfl_xor(v, o);
    return v;
}

__global__ __launch_bounds__(256) void softmax_causal_bf16(u16* __restrict__ scores, int S)
{
    __shared__ float red[4];
    const int gb = blockIdx.x;
    const int b = gb / S;
    const int i = gb - b * S;
    u16* row = scores + (size_t)b * S * S + (size_t)i * S;
    const int t = threadIdx.x;
    const int jlim = ((i >> 8) + 1) << 8;   // 256-tile granularity (gemm256 scores)
    const int j0 = t << 3;
    const bool act = j0 < jlim;

    float v[8];
    float mx = -1e30f;
    if (act) {
        u16x8v raw = *(const u16x8v*)(row + j0);
        #pragma unroll
        for (int e = 0; e < 8; ++e) {
            float x = bf2f(raw[e]);
            v[e] = (j0 + e <= i) ? x : -1e30f;
            mx = fmaxf(mx, v[e]);
        }
    } else {
        #pragma unroll
        for (int e = 0; e < 8; ++e) v[e] = -1e30f;
    }

    mx = waveMax(mx);
    const int wv = t >> 6;
    if ((t & 63) == 0) red[wv] = mx;
    __syncthreads();
    mx = fmaxf(fmaxf(red[0], red[1]), fmaxf(red[2], red[3]));
    __syncthreads();

    float sum = 0.f;
    if (act) {
        #pragma unroll
        for (int e = 0; e < 8; ++e) {
            float ex = (v[e] > -1e29f) ? __expf(v[e] - mx) : 0.f;
            v[e] = ex;
            sum += ex;
        }
    }
    sum = waveSum(sum);
    if ((t & 63) == 0) red[wv] = sum;
    __syncthreads();
    sum = red[0] + red[1] + red[2] + red[3];
    const float inv = 1.f / sum;

    if (act) {
        u16x8v o;
        #pragma unroll
        for (int e = 0; e < 8; ++e) o[e] = f2bf(v[e] * inv);
        *(u16x8v*)(row + j0) = o;
    }
}

// ---------------- host launcher ----------------
extern "C" void kernel_launch(void* const* d_in, const int* in_sizes, int n_in,
                              void* d_out, int out_size, void* d_ws, size_t ws_size,
                              hipStream_t stream)
{
    (void)in_sizes; (void)n_in; (void)out_size;
    const float* x  = (const float*)d_in[0];
    const float* Wq = (const float*)d_in[1];
    const float* bq = (const float*)d_in[2];
    const float* Wk = (const float*)d_in[3];
    const float* bk = (const float*)d_in[4];
    const float* Wv = (const float*)d_in[5];
    const float* bv = (const float*)d_in[6];
    const float* Wp = (const float*)d_in[7];
    const float* bp = (const float*)d_in[8];

    const int D = 1024, S = 2048, B = 4;
    const int M = B * S; // 8192

    char* p = (char*)d_ws;
    u16* xb   = (u16*)p; p += (size_t)M * D * 2;
    u16* Wcat = (u16*)p; p += (size_t)3 * D * D * 2;
    u16* Wpb  = (u16*)p; p += (size_t)D * D * 2;
    u16* qb   = (u16*)p; p += (size_t)M * D * 2;
    u16* kb   = (u16*)p; p += (size_t)M * D * 2;
    u16* vTb  = (u16*)p; p += (size_t)M * D * 2;   // vT[d][b*S+s], ld=M
    u16* vb   = (u16*)p;                           // dead after transpose
    u16* sc   = (u16*)p;                           // bf16 scores (overlaps vb)
    u16* attnb = xb;                               // alias: x dead after QKV

    const size_t fixed = (size_t)p - (size_t)d_ws;
    const size_t sb1   = (size_t)S * S * 2;
    const size_t vbsz  = (size_t)M * D * 2;
    int zb = (ws_size >= fixed + (4 * sb1 > vbsz ? 4 * sb1 : vbsz)) ? 4
           : (ws_size >= fixed + (2 * sb1 > vbsz ? 2 * sb1 : vbsz)) ? 2 : 1;

    hipFuncSetAttribute((const void*)gemm256<3, 1, 0>,
                        hipFuncAttributeMaxDynamicSharedMemorySize, LDS_256);
    hipFuncSetAttribute((const void*)gemm256<0, 1, 1>,
                        hipFuncAttributeMaxDynamicSharedMemorySize, LDS_256);
    hipFuncSetAttribute((const void*)gemm_nt2<0, 1, 0, 1>,
                        hipFuncAttributeMaxDynamicSharedMemorySize, LDS_NT2);
    hipFuncSetAttribute((const void*)gemm_nt2<1, 0, 0, 0>,
                        hipFuncAttributeMaxDynamicSharedMemorySize, LDS_NT2);

    // fp32 -> bf16
    cvt_bf16_kernel<<<(M * D / 4 + 255) / 256, 256, 0, stream>>>(x, xb, M * D / 4);
    cvt_w4_kernel<<<dim3((D * D / 4 + 255) / 256, 4), 256, 0, stream>>>(
        Wq, Wk, Wv, Wp, Wcat, Wpb, D * D / 4);

    // fused QKV: [q|k|v] = x Wcat^T + biases (q scaled); 256^2 2-phase kernel
    gemm256<3, 1, 0><<<dim3(3 * D / HBN, M / HBM), 512, LDS_256, stream>>>(
        xb, Wcat, qb, bq, kb, bk, vb, bv,
        M, 3 * D, D, D, D, D, 0, 0, 0, 0.03125f);

    // vT = v^T
    transpose16<<<dim3(D / 64, M / 64), 256, 0, stream>>>(vb, vTb, M, D);

    for (int b0 = 0; b0 < B; b0 += zb) {
        // scores = q k^T (lower-triangular 256-tiles only), bf16 out
        gemm256<0, 1, 1><<<dim3(S / HBN, S / HBM, zb), 512, LDS_256, stream>>>(
            qb + (size_t)b0 * S * D, kb + (size_t)b0 * S * D, sc, nullptr,
            nullptr, nullptr, nullptr, nullptr,
            S, S, D, D, D, S,
            (long long)S * D, (long long)S * D, (long long)S * S, 1.0f);
        // causal softmax in place (bf16 -> bf16 P), 256-tile jlim
        softmax_causal_bf16<<<zb * S, 256, 0, stream>>>(sc, S);
        // attn_out = P v  (A = P bf16 ld S; B = vT rows, K causally bounded)
        gemm_nt2<0, 1, 0, 1><<<dim3(D / GBN, S / GBM, zb), 512, LDS_NT2, stream>>>(
            sc, vTb + (size_t)b0 * S, attnb + (size_t)b0 * S * D,  nullptr,
            S, D, S, S, M, D,
            (long long)S * S, (long long)S, (long long)S * D, 1.0f);
    }

    // out = attn_out Wp^T + bp  (fp32 output)
    gemm_nt2<1, 0, 0, 0><<<dim3(D / GBN, M / GBM, 1), 512, LDS_NT2, stream>>>(
        attnb, Wpb, d_out, bp,
        M, D, D, D, D, D, 0, 0, 0, 1.0f);
}

// Round 9
// 199.285 us; speedup vs baseline: 1.1611x; 1.0045x over previous
//
#include <hip/hip_runtime.h>

#define AS1(p) ((const __attribute__((address_space(1))) void*)(p))
#define AS3(p) ((__attribute__((address_space(3))) void*)(p))

typedef unsigned short u16;
typedef __bf16 bf16x8 __attribute__((ext_vector_type(8)));
typedef short s16x8 __attribute__((ext_vector_type(8)));
typedef float f32x4 __attribute__((ext_vector_type(4)));
typedef unsigned short u16x4 __attribute__((ext_vector_type(4)));
typedef unsigned short u16x8v __attribute__((ext_vector_type(8)));

__device__ __forceinline__ u16 f2bf(float x) {
    unsigned u = __float_as_uint(x);
    unsigned r = (u + 0x7FFFu + ((u >> 16) & 1u)) >> 16;
    return (u16)r;
}
__device__ __forceinline__ float bf2f(u16 x) {
    return __uint_as_float(((unsigned)x) << 16);
}

template <typename V8>
__device__ __forceinline__ auto mfma_sel(V8 a, V8 b, f32x4 c, int)
    -> decltype(__builtin_amdgcn_mfma_f32_16x16x32_bf16(a, b, c, 0, 0, 0))
{
    return __builtin_amdgcn_mfma_f32_16x16x32_bf16(a, b, c, 0, 0, 0);
}
template <typename V8>
__device__ __forceinline__ f32x4 mfma_sel(V8 a, V8 b, f32x4 c, long)
{
    s16x8 a2 = __builtin_bit_cast(s16x8, a);
    s16x8 b2 = __builtin_bit_cast(s16x8, b);
    return __builtin_amdgcn_mfma_f32_16x16x32_bf16(a2, b2, c, 0, 0, 0);
}
__device__ __forceinline__ f32x4 mfma16x16x32(bf16x8 a, bf16x8 b, f32x4 c)
{
    return mfma_sel(a, b, c, 0);
}

// ---------------- fp32 -> bf16 converts ----------------
__global__ __launch_bounds__(256) void cvt_bf16_kernel(const float* __restrict__ in,
                                                       u16* __restrict__ out, int n4)
{
    int i = blockIdx.x * 256 + threadIdx.x;
    if (i >= n4) return;
    float4 f = ((const float4*)in)[i];
    u16x4 o;
    o.x = f2bf(f.x); o.y = f2bf(f.y); o.z = f2bf(f.z); o.w = f2bf(f.w);
    ((u16x4*)out)[i] = o;
}

__global__ __launch_bounds__(256) void cvt_w4_kernel(const float* __restrict__ Wq,
                                                     const float* __restrict__ Wk,
                                                     const float* __restrict__ Wv,
                                                     const float* __restrict__ Wp,
                                                     u16* __restrict__ Wcat,
                                                     u16* __restrict__ Wpb, int n4)
{
    int i = blockIdx.x * 256 + threadIdx.x;
    if (i >= n4) return;
    const int by = blockIdx.y;
    const float* src = (by == 0) ? Wq : (by == 1) ? Wk : (by == 2) ? Wv : Wp;
    u16* dst = (by == 3) ? Wpb : (Wcat + (size_t)by * n4 * 4);
    float4 f = ((const float4*)src)[i];
    u16x4 o;
    o.x = f2bf(f.x); o.y = f2bf(f.y); o.z = f2bf(f.z); o.w = f2bf(f.w);
    ((u16x4*)dst)[i] = o;
}

// ---------------- bf16 transpose: in[R][C] -> out[C][R], 64x64 tiles ----------------
__global__ __launch_bounds__(256) void transpose16(const u16* __restrict__ in,
                                                   u16* __restrict__ out, int R, int C)
{
    __shared__ u16 tl[64][65];
    const int tr0 = blockIdx.y * 64, tc0 = blockIdx.x * 64;
    const int t = threadIdx.x;
    const int r = t >> 2, c4 = (t & 3) << 4;

    const u16* src = in + (size_t)(tr0 + r) * C + tc0 + c4;
    u16x8v a0 = *(const u16x8v*)src;
    u16x8v a1 = *(const u16x8v*)(src + 8);
    #pragma unroll
    for (int j = 0; j < 8; ++j) { tl[r][c4 + j] = a0[j]; tl[r][c4 + 8 + j] = a1[j]; }
    __syncthreads();

    u16x8v b0, b1;
    #pragma unroll
    for (int j = 0; j < 8; ++j) { b0[j] = tl[c4 + j][r]; b1[j] = tl[c4 + 8 + j][r]; }
    u16* dst = out + (size_t)(tc0 + r) * R + tr0 + c4;
    *(u16x8v*)dst = b0;
    *(u16x8v*)(dst + 8) = b1;
}

// ============ m97-structure NT GEMM: 128x128, BK=64, 256 threads ============
// Single-buffered 32 KB static LDS, 2 barriers per K-tile. The win vs the
// 512-thread/144KB line: 3 blocks/CU co-resident (m97: ~912 TF) — inter-block
// overlap hides the staging drain that counted-vmcnt only partially hid at
// 1 block/CU. 4 waves (2Mx2N), per-wave 64x64 out.
// T2 swizzle (rule 21): linear LDS dest, inverse-XOR'd global SOURCE slot,
// XOR'd read: slot16B ^= (row&7). Conflict-free (verified r3: conflicts=0).
// BIAS: 0 none, 1 bias[col], 3 fused QKV (q scaled / k / v row-major).
// CSKIP: skip tiles above causal diagonal. CKB: K bounded at m0+128,
// row-blocks reversed so longest-K first. SWZ: bijective XCD swizzle
// (requires nwg % 8 == 0).
#define MBM 128
#define MBK 64

template <int BIAS, int OUTBF16, int CSKIP, int CKB, int SWZ>
__global__ __launch_bounds__(256, 3)
void gemm128(const u16* __restrict__ A, const u16* __restrict__ B,
             void* __restrict__ Cv, const float* __restrict__ bias,
             void* __restrict__ C2, const float* __restrict__ bias2,
             void* __restrict__ C3, const float* __restrict__ bias3,
             int M, int N, int K, int lda, int ldb, int ldc,
             long long sA, long long sB, long long sC, float scale)
{
    __shared__ u16 lA[MBM * MBK];
    __shared__ u16 lB[MBM * MBK];

    int bx = blockIdx.x, by = blockIdx.y;
    if (SWZ) {
        const int gx = gridDim.x;
        const int nwg = gx * gridDim.y;
        int id = by * gx + bx;
        id = (id & 7) * (nwg >> 3) + (id >> 3);
        bx = id % gx; by = id / gx;
    }
    if (CKB) by = gridDim.y - 1 - by;       // longest-K blocks first
    const int m0 = by * MBM;
    const int n0 = bx * MBM;
    if (CSKIP && n0 > m0 + MBM - 1) return;

    const int z = blockIdx.z;
    A += (size_t)z * (size_t)sA;
    B += (size_t)z * (size_t)sB;

    const int t = threadIdx.x;
    const int lane = t & 63;
    const int w = t >> 6;
    const int wr = w >> 1;           // 0..1 (M)
    const int wc = w & 1;            // 0..1 (N)
    const int fr = lane & 15, fg = lane >> 4;

    int Keff = K;
    if (CKB) { Keff = m0 + MBM; if (Keff > K) Keff = K; }
    const int nk = Keff / MBK;

    f32x4 acc[4][4] = {};

    for (int kt = 0; kt < nk; ++kt) {
        const int k0 = kt * MBK;
        // stage A,B (128x64 each): 1024 16B chunks apiece, 4 rounds of 256
        #pragma unroll
        for (int i = 0; i < 4; ++i) {
            int c = t + i * 256;
            int row = c >> 3;
            int sl = (c & 7) ^ (row & 7);      // inverse-swizzled source slot
            __builtin_amdgcn_global_load_lds(
                AS1(A + (size_t)(m0 + row) * lda + k0 + sl * 8),
                AS3(&lA[c * 8]), 16, 0, 0);
            __builtin_amdgcn_global_load_lds(
                AS1(B + (size_t)(n0 + row) * ldb + k0 + sl * 8),
                AS3(&lB[c * 8]), 16, 0, 0);
        }
        __syncthreads();                        // drains vmcnt: tile staged

        #pragma unroll
        for (int kk = 0; kk < MBK; kk += 32) {
            const int cs = (kk >> 3) + fg;      // column 16B-slot 0..7
            bf16x8 af[4], bfv[4];
            #pragma unroll
            for (int mi = 0; mi < 4; ++mi) {
                int row = wr * 64 + mi * 16 + fr;
                af[mi] = *(const bf16x8*)&lA[row * 64 + ((cs ^ (row & 7)) << 3)];
            }
            #pragma unroll
            for (int ni = 0; ni < 4; ++ni) {
                int row = wc * 64 + ni * 16 + fr;
                bfv[ni] = *(const bf16x8*)&lB[row * 64 + ((cs ^ (row & 7)) << 3)];
            }
            __builtin_amdgcn_s_setprio(1);
            #pragma unroll
            for (int mi = 0; mi < 4; ++mi)
                #pragma unroll
                for (int ni = 0; ni < 4; ++ni)
                    acc[mi][ni] = mfma16x16x32(af[mi], bfv[ni], acc[mi][ni]);
            __builtin_amdgcn_s_setprio(0);
        }
        __syncthreads();                        // reads done before next stage
    }

    // ---- epilogue: C/D layout col=lane&15, row=(lane>>4)*4+reg ----
    #pragma unroll
    for (int mi = 0; mi < 4; ++mi) {
        #pragma unroll
        for (int ni = 0; ni < 4; ++ni) {
            int col = n0 + wc * 64 + ni * 16 + fr;
            int row0 = m0 + wr * 64 + mi * 16 + fg * 4;
            if (BIAS == 3) {
                // fused QKV: seg 0 -> q (scaled), 1 -> k, 2 -> v (row-major)
                int seg = col >> 10;
                int ccol = col & 1023;
                u16* dst = (seg == 0) ? (u16*)Cv : (seg == 1) ? (u16*)C2 : (u16*)C3;
                float b = ((seg == 0) ? bias : (seg == 1) ? bias2 : bias3)[ccol];
                float sc_ = (seg == 0) ? scale : 1.f;
                #pragma unroll
                for (int j = 0; j < 4; ++j)
                    dst[(size_t)(row0 + j) * 1024 + ccol] =
                        f2bf((acc[mi][ni][j] + b) * sc_);
            } else {
                float bval = (BIAS == 1) ? bias[col] : 0.f;
                #pragma unroll
                for (int j = 0; j < 4; ++j) {
                    float v = (acc[mi][ni][j] + bval) * scale;
                    size_t off = (size_t)z * (size_t)sC + (size_t)(row0 + j) * ldc + col;
                    if (OUTBF16) ((u16*)Cv)[off] = f2bf(v);
                    else         ((float*)Cv)[off] = v;
                }
            }
        }
    }
}

// ---------------- causal softmax on bf16 scores, in place ----------------
__device__ __forceinline__ float waveMax(float v) {
    #pragma unroll
    for (int o = 32; o > 0; o >>= 1) v = fmaxf(v, __shfl_xor(v, o));
    return v;
}
__device__ __forceinline__ float waveSum(float v) {
    #pragma unroll
    for (int o = 32; o > 0; o >>= 1) v += __shfl_xor(v, o);
    return v;
}

__global__ __launch_bounds__(256) void softmax_causal_bf16(u16* __restrict__ scores, int S)
{
    __shared__ float red[4];
    const int gb = blockIdx.x;
    const int b = gb / S;
    const int i = gb - b * S;
    u16* row = scores + (size_t)b * S * S + (size_t)i * S;
    const int t = threadIdx.x;
    const int jlim = ((i >> 7) + 1) << 7;   // 128-tile granularity (= PV Keff)
    const int j0 = t << 3;
    const bool act = j0 < jlim;

    float v[8];
    float mx = -1e30f;
    if (act) {
        u16x8v raw = *(const u16x8v*)(row + j0);
        #pragma unroll
        for (int e = 0; e < 8; ++e) {
            float x = bf2f(raw[e]);
            v[e] = (j0 + e <= i) ? x : -1e30f;
            mx = fmaxf(mx, v[e]);
        }
    } else {
        #pragma unroll
        for (int e = 0; e < 8; ++e) v[e] = -1e30f;
    }

    mx = waveMax(mx);
    const int wv = t >> 6;
    if ((t & 63) == 0) red[wv] = mx;
    __syncthreads();
    mx = fmaxf(fmaxf(red[0], red[1]), fmaxf(red[2], red[3]));
    __syncthreads();

    float sum = 0.f;
    if (act) {
        #pragma unroll
        for (int e = 0; e < 8; ++e) {
            float ex = (v[e] > -1e29f) ? __expf(v[e] - mx) : 0.f;
            v[e] = ex;
            sum += ex;
        }
    }
    sum = waveSum(sum);
    if ((t & 63) == 0) red[wv] = sum;
    __syncthreads();
    sum = red[0] + red[1] + red[2] + red[3];
    const float inv = 1.f / sum;

    if (act) {
        u16x8v o;
        #pragma unroll
        for (int e = 0; e < 8; ++e) o[e] = f2bf(v[e] * inv);
        *(u16x8v*)(row + j0) = o;
    }
}

// ---------------- host launcher ----------------
extern "C" void kernel_launch(void* const* d_in, const int* in_sizes, int n_in,
                              void* d_out, int out_size, void* d_ws, size_t ws_size,
                              hipStream_t stream)
{
    (void)in_sizes; (void)n_in; (void)out_size;
    const float* x  = (const float*)d_in[0];
    const float* Wq = (const float*)d_in[1];
    const float* bq = (const float*)d_in[2];
    const float* Wk = (const float*)d_in[3];
    const float* bk = (const float*)d_in[4];
    const float* Wv = (const float*)d_in[5];
    const float* bv = (const float*)d_in[6];
    const float* Wp = (const float*)d_in[7];
    const float* bp = (const float*)d_in[8];

    const int D = 1024, S = 2048, B = 4;
    const int M = B * S; // 8192

    char* p = (char*)d_ws;
    u16* xb   = (u16*)p; p += (size_t)M * D * 2;
    u16* Wcat = (u16*)p; p += (size_t)3 * D * D * 2;
    u16* Wpb  = (u16*)p; p += (size_t)D * D * 2;
    u16* qb   = (u16*)p; p += (size_t)M * D * 2;
    u16* kb   = (u16*)p; p += (size_t)M * D * 2;
    u16* vTb  = (u16*)p; p += (size_t)M * D * 2;   // vT[d][b*S+s], ld=M
    u16* vb   = (u16*)p;                           // dead after transpose
    u16* sc   = (u16*)p;                           // bf16 scores (overlaps vb)
    u16* attnb = xb;                               // alias: x dead after QKV

    const size_t fixed = (size_t)p - (size_t)d_ws;
    const size_t sb1   = (size_t)S * S * 2;
    const size_t vbsz  = (size_t)M * D * 2;
    int zb = (ws_size >= fixed + (4 * sb1 > vbsz ? 4 * sb1 : vbsz)) ? 4
           : (ws_size >= fixed + (2 * sb1 > vbsz ? 2 * sb1 : vbsz)) ? 2 : 1;

    // fp32 -> bf16
    cvt_bf16_kernel<<<(M * D / 4 + 255) / 256, 256, 0, stream>>>(x, xb, M * D / 4);
    cvt_w4_kernel<<<dim3((D * D / 4 + 255) / 256, 4), 256, 0, stream>>>(
        Wq, Wk, Wv, Wp, Wcat, Wpb, D * D / 4);

    // fused QKV: [q|k|v] = x Wcat^T + biases (q scaled); nwg=1536, XCD-swizzled
    gemm128<3, 1, 0, 0, 1><<<dim3(3 * D / MBM, M / MBM), 256, 0, stream>>>(
        xb, Wcat, qb, bq, kb, bk, vb, bv,
        M, 3 * D, D, D, D, D, 0, 0, 0, 0.03125f);

    // vT = v^T
    transpose16<<<dim3(D / 64, M / 64), 256, 0, stream>>>(vb, vTb, M, D);

    for (int b0 = 0; b0 < B; b0 += zb) {
        // scores = q k^T (lower-triangular 128-tiles only), bf16 out
        gemm128<0, 1, 1, 0, 0><<<dim3(S / MBM, S / MBM, zb), 256, 0, stream>>>(
            qb + (size_t)b0 * S * D, kb + (size_t)b0 * S * D, sc, nullptr,
            nullptr, nullptr, nullptr, nullptr,
            S, S, D, D, D, S,
            (long long)S * D, (long long)S * D, (long long)S * S, 1.0f);
        // causal softmax in place (bf16 -> bf16 P)
        softmax_causal_bf16<<<zb * S, 256, 0, stream>>>(sc, S);
        // attn_out = P v  (A = P bf16 ld S; B = vT rows, K causally bounded)
        gemm128<0, 1, 0, 1, 0><<<dim3(D / MBM, S / MBM, zb), 256, 0, stream>>>(
            sc, vTb + (size_t)b0 * S, attnb + (size_t)b0 * S * D, nullptr,
            nullptr, nullptr, nullptr, nullptr,
            S, D, S, S, M, D,
            (long long)S * S, (long long)S, (long long)S * D, 1.0f);
    }

    // out = attn_out Wp^T + bp  (fp32 output); nwg=512, XCD-swizzled
    gemm128<1, 0, 0, 0, 1><<<dim3(D / MBM, M / MBM), 256, 0, stream>>>(
        attnb, Wpb, d_out, bp, nullptr, nullptr, nullptr, nullptr,
        M, D, D, D, D, D, 0, 0, 0, 1.0f);
}